// Round 1
// 1368.725 us; speedup vs baseline: 1.0281x; 1.0281x over previous
//
#include <hip/hip_runtime.h>
#include <cstdint>
#include <cstddef>

typedef __bf16 bf16;
typedef __bf16 bf16x4 __attribute__((ext_vector_type(4)));
typedef __bf16 bf16x8 __attribute__((ext_vector_type(8)));
typedef float f32x4 __attribute__((ext_vector_type(4)));

static_assert(sizeof(bf16x8) == 16, "bf16x8 must be 16B");

#define NTOK 100352   // 32 * 3136
#define CDIM 384

#define AS1(p) ((const __attribute__((address_space(1))) void*)(p))
#define AS3(p) ((__attribute__((address_space(3))) void*)(p))

// ---------------- fp32 -> bf16 weight conversion ----------------
__global__ __launch_bounds__(256) void cvt_k(const float* __restrict__ in,
                                             bf16* __restrict__ out, int n)
{
    const int i = (blockIdx.x * 256 + threadIdx.x) * 4;
    if (i < n) {
        const float4 v = *(const float4*)(in + i);
        bf16x4 o;
        o[0] = (bf16)v.x; o[1] = (bf16)v.y; o[2] = (bf16)v.z; o[3] = (bf16)v.w;
        *(bf16x4*)(out + i) = o;
    }
}

// ---------------- LayerNorm, fp32 input -> bf16 output (row per wave) ----------------
__global__ __launch_bounds__(256) void ln32_k(const float* __restrict__ x,
    const float* __restrict__ g, const float* __restrict__ b, bf16* __restrict__ y)
{
    const int wave = threadIdx.x >> 6, lane = threadIdx.x & 63;
    const size_t row = (size_t)blockIdx.x * 4 + wave;
    const float2* xr = (const float2*)(x + row * CDIM);
    float v[6];
    float s = 0.f, s2 = 0.f;
#pragma unroll
    for (int i = 0; i < 3; i++) {
        const float2 t = xr[lane + i * 64];
        v[2 * i] = t.x; v[2 * i + 1] = t.y;
        s += t.x + t.y; s2 += t.x * t.x + t.y * t.y;
    }
#pragma unroll
    for (int off = 32; off > 0; off >>= 1) {
        s  += __shfl_xor(s, off);
        s2 += __shfl_xor(s2, off);
    }
    const float mu   = s * (1.f / CDIM);
    const float rstd = rsqrtf(s2 * (1.f / CDIM) - mu * mu + 1e-5f);
    const float2* gu = (const float2*)g;
    const float2* bu = (const float2*)b;
    uint32_t* yu = (uint32_t*)(y + row * CDIM);
#pragma unroll
    for (int i = 0; i < 3; i++) {
        const float2 gg = gu[lane + i * 64], bb = bu[lane + i * 64];
        const float o0 = (v[2 * i] - mu) * rstd * gg.x + bb.x;
        const float o1 = (v[2 * i + 1] - mu) * rstd * gg.y + bb.y;
        const uint32_t pk = (uint32_t)__builtin_bit_cast(unsigned short, (bf16)o0)
                          | ((uint32_t)__builtin_bit_cast(unsigned short, (bf16)o1) << 16);
        yu[lane + i * 64] = pk;
    }
}

// ---------------- GEMM: C = A(MxK) @ B(NxK)^T + bias [+ gelu | + res] ----------------
// 128x128 tile, BK=32, 4 waves (2x2), each wave 64x64 via 4x4 of 16x16x32 bf16 MFMA.
// Staging: global_load_lds width-16 (m97 structure). LDS layout [128][32] bf16,
// linear in tid (thread t owns bytes [t*16, t*16+16) of each 64-row panel) —
// exactly the wave-uniform-base + lane*16 pattern global_load_lds requires.
// Block swizzle: bijective XCD remap (m204) on y-major linear id so each XCD
// gets a contiguous stripe of M-tiles -> A panels stay in one XCD's L2.
// EPI: 0 = +bias, 1 = +bias then exact GELU, 2 = +bias +res(fp32)
template <int EPI, typename TO>
__global__ __launch_bounds__(256) void gemm_bt(
    const bf16* __restrict__ A, const bf16* __restrict__ Bm,
    const float* __restrict__ bias, const float* __restrict__ res,
    TO* __restrict__ Cc, int N, int K)
{
    __shared__ __align__(16) bf16 aT[128 * 32];
    __shared__ __align__(16) bf16 bT[128 * 32];
    const int tid = threadIdx.x;

    // XCD-bijective swizzle (8 XCDs). orig -> swz, contiguous chunk per XCD.
    const int gx = gridDim.x;
    const int nwg = gx * gridDim.y;
    const int orig = blockIdx.y * gx + blockIdx.x;
    const int q = nwg >> 3, r = nwg & 7;
    const int xcd = orig & 7, lid = orig >> 3;
    const int swz = (xcd < r ? xcd * (q + 1) : r * (q + 1) + (xcd - r) * q) + lid;
    const int m0 = (swz / gx) * 128, n0 = (swz % gx) * 128;

    const int wave = tid >> 6, lane = tid & 63;
    const int wm = (wave >> 1) * 64, wn = (wave & 1) * 64;
    const int lm = lane & 15, lk = (lane >> 4) * 8;

    // staging source coords (identical linear order to LDS dest):
    const int sr = tid >> 2;              // row 0..63 within panel
    const int sc = (tid & 3) * 8;         // col element 0,8,16,24

    const bf16* Ap0 = A + (size_t)(m0 + sr) * K + sc;
    const bf16* Ap1 = A + (size_t)(m0 + sr + 64) * K + sc;
    const bf16* Bp0 = Bm + (size_t)(n0 + sr) * K + sc;
    const bf16* Bp1 = Bm + (size_t)(n0 + sr + 64) * K + sc;
    // wave-uniform LDS bases: wave w covers rows [w*16, w*16+16) of each panel
    bf16* aL0 = &aT[(wave * 16) * 32];
    bf16* aL1 = &aT[(64 + wave * 16) * 32];
    bf16* bL0 = &bT[(wave * 16) * 32];
    bf16* bL1 = &bT[(64 + wave * 16) * 32];

    f32x4 acc[4][4] = {};

    for (int k0 = 0; k0 < K; k0 += 32) {
        __syncthreads();  // previous iteration's ds_reads done before overwrite
        __builtin_amdgcn_global_load_lds(AS1(Ap0 + k0), AS3(aL0), 16, 0, 0);
        __builtin_amdgcn_global_load_lds(AS1(Ap1 + k0), AS3(aL1), 16, 0, 0);
        __builtin_amdgcn_global_load_lds(AS1(Bp0 + k0), AS3(bL0), 16, 0, 0);
        __builtin_amdgcn_global_load_lds(AS1(Bp1 + k0), AS3(bL1), 16, 0, 0);
        __syncthreads();  // implies vmcnt(0): staged data visible
        bf16x8 af[4], bfr[4];
#pragma unroll
        for (int i = 0; i < 4; i++)
            af[i] = *(const bf16x8*)&aT[(wm + i * 16 + lm) * 32 + lk];
#pragma unroll
        for (int i = 0; i < 4; i++)
            bfr[i] = *(const bf16x8*)&bT[(wn + i * 16 + lm) * 32 + lk];
#pragma unroll
        for (int mi = 0; mi < 4; mi++)
#pragma unroll
            for (int ni = 0; ni < 4; ni++)
                acc[mi][ni] = __builtin_amdgcn_mfma_f32_16x16x32_bf16(
                    af[mi], bfr[ni], acc[mi][ni], 0, 0, 0);
    }

    // C/D layout: col = lane&15, row = (lane>>4)*4 + reg
    const int rb = m0 + wm + (lane >> 4) * 4;
    const int cb = n0 + wn + lm;
#pragma unroll
    for (int ni = 0; ni < 4; ni++) {
        const int col = cb + ni * 16;
        const float bv = bias[col];
#pragma unroll
        for (int mi = 0; mi < 4; mi++) {
#pragma unroll
            for (int r2 = 0; r2 < 4; r2++) {
                const int row = rb + mi * 16 + r2;
                float v = acc[mi][ni][r2] + bv;
                if (EPI == 1) v = 0.5f * v * (1.f + erff(v * 0.70710678118654752f));
                if (EPI == 2) v += res[(size_t)row * N + col];
                Cc[(size_t)row * N + col] = (TO)v;
            }
        }
    }
}

// ---------------- Windowed attention: one block per (head, window) ----------------
// qkv/out pointers are CHUNK-LOCAL (a whole number of images each).
__global__ __launch_bounds__(256) void attn_k(const bf16* __restrict__ qkv,
    const float* __restrict__ rpb, bf16* __restrict__ out)
{
    const int hd = blockIdx.x;          // 0..11
    const int w  = blockIdx.y;          // 0..64*imgs-1
    const int bb = w >> 6, win = w & 63, wy = win >> 3, wx = win & 7;
    __shared__ int   toks[49];
    __shared__ float biasS[169];
    __shared__ __align__(16) float ks[49][36];
    __shared__ __align__(16) float vs[49][36];
    __shared__ float S[49][50];
    const int tid = threadIdx.x;
    if (tid < 49)
        toks[tid] = bb * 3136 + (wy * 7 + tid / 7) * 56 + wx * 7 + tid % 7;
    if (tid < 169) biasS[tid] = rpb[tid * 12 + hd];
    __syncthreads();
    // stage K,V (fp32) into LDS, 16B global loads
    for (int t = tid; t < 49 * 4; t += 256) {
        const int r = t >> 2, dc = (t & 3) * 8;
        const bf16* p = qkv + (size_t)toks[r] * 1152 + hd * 32 + dc;
        const bf16x8 kv = *(const bf16x8*)(p + 384);
        const bf16x8 vv = *(const bf16x8*)(p + 768);
#pragma unroll
        for (int e = 0; e < 8; e++) { ks[r][dc + e] = (float)kv[e]; vs[r][dc + e] = (float)vv[e]; }
    }
    __syncthreads();
    const int i = tid >> 2, q4 = tid & 3;   // 4 threads cooperate per query row
    if (i < 49) {
        float qr[32];
        const bf16* qp = qkv + (size_t)toks[i] * 1152 + hd * 32;
#pragma unroll
        for (int c = 0; c < 4; c++) {
            const bf16x8 qv = *(const bf16x8*)(qp + c * 8);
#pragma unroll
            for (int e = 0; e < 8; e++) qr[c * 8 + e] = (float)qv[e] * 0.1767766952966369f;
        }
        const int iy = i / 7, ix = i % 7;
        for (int j = q4; j < 49; j += 4) {
            float dot = 0.f;
#pragma unroll
            for (int dc = 0; dc < 8; dc++) {
                const float4 kk = *(const float4*)&ks[j][dc * 4];
                dot += qr[dc*4]*kk.x + qr[dc*4+1]*kk.y + qr[dc*4+2]*kk.z + qr[dc*4+3]*kk.w;
            }
            S[i][j] = dot + biasS[(iy - j / 7 + 6) * 13 + (ix - j % 7 + 6)];
        }
    }
    __syncthreads();
    if (tid < 49) {
        float mx = -1e30f;
        for (int j = 0; j < 49; j++) mx = fmaxf(mx, S[tid][j]);
        float sum = 0.f;
        for (int j = 0; j < 49; j++) { const float e = __expf(S[tid][j] - mx); S[tid][j] = e; sum += e; }
        const float inv = 1.f / sum;
        for (int j = 0; j < 49; j++) S[tid][j] *= inv;
    }
    __syncthreads();
    if (i < 49) {
        const int dc = q4 * 8;
        float acc[8] = {};
        for (int j = 0; j < 49; j++) {
            const float p = S[i][j];
            const float4 v0 = *(const float4*)&vs[j][dc];
            const float4 v1 = *(const float4*)&vs[j][dc + 4];
            acc[0] += p * v0.x; acc[1] += p * v0.y; acc[2] += p * v0.z; acc[3] += p * v0.w;
            acc[4] += p * v1.x; acc[5] += p * v1.y; acc[6] += p * v1.z; acc[7] += p * v1.w;
        }
        bf16x8 pk;
#pragma unroll
        for (int e = 0; e < 8; e++) pk[e] = (bf16)acc[e];
        *(bf16x8*)(out + (size_t)toks[i] * CDIM + hd * 32 + dc) = pk;
    }
}

extern "C" void kernel_launch(void* const* d_in, const int* in_sizes, int n_in,
                              void* d_out, int out_size, void* d_ws, size_t ws_size,
                              hipStream_t stream) {
    // All float tensors are fp32 per the reference; OUTPUT IS FP32 TOO.
    const float* x      = (const float*)d_in[0];
    const float* n1g    = (const float*)d_in[1];
    const float* n1b    = (const float*)d_in[2];
    const float* qkv_w  = (const float*)d_in[3];
    const float* qkv_b  = (const float*)d_in[4];
    const float* rpb    = (const float*)d_in[5];
    const float* proj_w = (const float*)d_in[6];
    const float* proj_b = (const float*)d_in[7];
    const float* n2g    = (const float*)d_in[8];
    const float* n2b    = (const float*)d_in[9];
    const float* fc1_w  = (const float*)d_in[10];
    const float* fc1_b  = (const float*)d_in[11];
    const float* fc2_w  = (const float*)d_in[12];
    const float* fc2_b  = (const float*)d_in[13];
    float* out = (float*)d_out;

    // Workspace layout:
    //   [0, 3538944):            bf16 weights (qkv 442368 | proj 147456 | fc1 589824 | fc2 589824)
    //   [3538944, +rowsC*768):   bufH  (LN out / attn-out chunk, bf16)
    //   [.., +rowsC*3072):       bufB  (qkv chunk 2304 B/row or fc1-out chunk 3072 B/row)
    // x1 (post-attention residual stream, fp32) lives in d_out.
    const size_t wBytes = 3538944;
    int nc = 16;
    for (int c : {1, 2, 4, 8}) {
        if (wBytes + ((size_t)NTOK / c) * 3840 <= ws_size) { nc = c; break; }
    }
    const int rowsC = NTOK / nc;
    const int imgsC = 32 / nc;

    char* ws = (char*)d_ws;
    bf16* wqkv  = (bf16*)ws;
    bf16* wproj = wqkv + 442368;
    bf16* wfc1  = wproj + 147456;
    bf16* wfc2  = wfc1 + 589824;
    bf16* bufH  = (bf16*)(ws + wBytes);
    bf16* bufB  = bufH + (size_t)rowsC * CDIM;
    float* x1   = out;                  // fp32 residual stream in d_out

    // 0) weights fp32 -> bf16
    cvt_k<<<442368 / 1024, 256, 0, stream>>>(qkv_w, wqkv, 442368);
    cvt_k<<<147456 / 1024, 256, 0, stream>>>(proj_w, wproj, 147456);
    cvt_k<<<589824 / 1024, 256, 0, stream>>>(fc1_w, wfc1, 589824);
    cvt_k<<<589824 / 1024, 256, 0, stream>>>(fc2_w, wfc2, 589824);

    // 1) attention path, chunked over images
    for (int c = 0; c < nc; c++) {
        const size_t ro = (size_t)c * rowsC;
        ln32_k<<<rowsC / 4, 256, 0, stream>>>(x + ro * CDIM, n1g, n1b, bufH);
        gemm_bt<0, bf16><<<dim3(1152 / 128, rowsC / 128), 256, 0, stream>>>(
            bufH, wqkv, qkv_b, nullptr, bufB, 1152, 384);
        attn_k<<<dim3(12, 64 * imgsC), 256, 0, stream>>>(bufB, rpb, bufH);
        // x1 = x + attn_out @ proj_w^T + proj_b   (fp32, into d_out)
        gemm_bt<2, float><<<dim3(384 / 128, rowsC / 128), 256, 0, stream>>>(
            bufH, wproj, proj_b, x + ro * CDIM, x1 + ro * CDIM, 384, 384);
    }
    // 2) MLP path, chunked
    for (int c = 0; c < nc; c++) {
        const size_t ro = (size_t)c * rowsC;
        ln32_k<<<rowsC / 4, 256, 0, stream>>>(x1 + ro * CDIM, n2g, n2b, bufH);
        gemm_bt<1, bf16><<<dim3(1536 / 128, rowsC / 128), 256, 0, stream>>>(
            bufH, wfc1, fc1_b, nullptr, bufB, 1536, 384);
        // out = x1 + gelu(h2@fc1^T+b1)@fc2^T + b2  (fp32; res==dst, read-before-write)
        gemm_bt<2, float><<<dim3(384 / 128, rowsC / 128), 256, 0, stream>>>(
            bufB, wfc2, fc2_b, x1 + ro * CDIM, out + ro * CDIM, 384, 1536);
    }
}

// Round 2
// 1318.752 us; speedup vs baseline: 1.0671x; 1.0379x over previous
//
#include <hip/hip_runtime.h>
#include <cstdint>
#include <cstddef>

typedef __bf16 bf16;
typedef __bf16 bf16x4 __attribute__((ext_vector_type(4)));
typedef __bf16 bf16x8 __attribute__((ext_vector_type(8)));
typedef float f32x4 __attribute__((ext_vector_type(4)));

static_assert(sizeof(bf16x8) == 16, "bf16x8 must be 16B");

#define NTOK 100352   // 32 * 3136
#define CDIM 384

// ---------------- fp32 -> bf16 weight conversion ----------------
__global__ __launch_bounds__(256) void cvt_k(const float* __restrict__ in,
                                             bf16* __restrict__ out, int n)
{
    const int i = (blockIdx.x * 256 + threadIdx.x) * 4;
    if (i < n) {
        const float4 v = *(const float4*)(in + i);
        bf16x4 o;
        o[0] = (bf16)v.x; o[1] = (bf16)v.y; o[2] = (bf16)v.z; o[3] = (bf16)v.w;
        *(bf16x4*)(out + i) = o;
    }
}

// ---------------- LayerNorm, fp32 input -> bf16 output (row per wave) ----------------
__global__ __launch_bounds__(256) void ln32_k(const float* __restrict__ x,
    const float* __restrict__ g, const float* __restrict__ b, bf16* __restrict__ y)
{
    const int wave = threadIdx.x >> 6, lane = threadIdx.x & 63;
    const size_t row = (size_t)blockIdx.x * 4 + wave;
    const float2* xr = (const float2*)(x + row * CDIM);
    float v[6];
    float s = 0.f, s2 = 0.f;
#pragma unroll
    for (int i = 0; i < 3; i++) {
        const float2 t = xr[lane + i * 64];
        v[2 * i] = t.x; v[2 * i + 1] = t.y;
        s += t.x + t.y; s2 += t.x * t.x + t.y * t.y;
    }
#pragma unroll
    for (int off = 32; off > 0; off >>= 1) {
        s  += __shfl_xor(s, off);
        s2 += __shfl_xor(s2, off);
    }
    const float mu   = s * (1.f / CDIM);
    const float rstd = rsqrtf(s2 * (1.f / CDIM) - mu * mu + 1e-5f);
    const float2* gu = (const float2*)g;
    const float2* bu = (const float2*)b;
    uint32_t* yu = (uint32_t*)(y + row * CDIM);
#pragma unroll
    for (int i = 0; i < 3; i++) {
        const float2 gg = gu[lane + i * 64], bb = bu[lane + i * 64];
        const float o0 = (v[2 * i] - mu) * rstd * gg.x + bb.x;
        const float o1 = (v[2 * i + 1] - mu) * rstd * gg.y + bb.y;
        const uint32_t pk = (uint32_t)__builtin_bit_cast(unsigned short, (bf16)o0)
                          | ((uint32_t)__builtin_bit_cast(unsigned short, (bf16)o1) << 16);
        yu[lane + i * 64] = pk;
    }
}

// ---------------- GEMM: C = A(MxK) @ B(NxK)^T + bias [+ gelu | + res] ----------------
// 128x128 tile, BK=32, 4 waves (2x2), each wave 64x64 via 4x4 of 16x16x32 bf16 MFMA.
// Staging: reg-staged (bf16x8 global loads -> ds_write). The loads for iteration
// k+1 issue at the loop top, overlapping the previous iteration's MFMA + bar1 —
// measured faster than global_load_lds here (K=384: too few iters to hide the
// per-iter vmcnt(0) drain that global_load_lds forces at bar2).
// Block swizzle: bijective XCD remap (m204) on y-major linear id so each XCD
// gets a contiguous stripe of M-tiles -> A panels stay in one XCD's L2
// (measured: FETCH_SIZE 308 MB -> 60 MB on fc1).
// EPI: 0 = +bias, 1 = +bias then GELU (tanh form), 2 = +bias +res(fp32)
template <int EPI, typename TO>
__global__ __launch_bounds__(256) void gemm_bt(
    const bf16* __restrict__ A, const bf16* __restrict__ Bm,
    const float* __restrict__ bias, const float* __restrict__ res,
    TO* __restrict__ Cc, int N, int K)
{
    __shared__ __align__(16) bf16 aT[128 * 32];
    __shared__ __align__(16) bf16 bT[128 * 32];
    const int tid = threadIdx.x;

    // XCD-bijective swizzle (8 XCDs). orig -> swz, contiguous chunk per XCD.
    const int gx = gridDim.x;
    const int nwg = gx * gridDim.y;
    const int orig = blockIdx.y * gx + blockIdx.x;
    const int q = nwg >> 3, r = nwg & 7;
    const int xcd = orig & 7, lid = orig >> 3;
    const int swz = (xcd < r ? xcd * (q + 1) : r * (q + 1) + (xcd - r) * q) + lid;
    const int m0 = (swz / gx) * 128, n0 = (swz % gx) * 128;

    const int wave = tid >> 6, lane = tid & 63;
    const int wm = (wave >> 1) * 64, wn = (wave & 1) * 64;
    const int lm = lane & 15, lk = (lane >> 4) * 8;
    const int r0 = tid >> 2, cc0 = (tid & 3) * 8;

    f32x4 acc[4][4] = {};

    const bf16* Ap0 = A + (size_t)(m0 + r0) * K + cc0;
    const bf16* Ap1 = A + (size_t)(m0 + r0 + 64) * K + cc0;
    const bf16* Bp0 = Bm + (size_t)(n0 + r0) * K + cc0;
    const bf16* Bp1 = Bm + (size_t)(n0 + r0 + 64) * K + cc0;

    for (int k0 = 0; k0 < K; k0 += 32) {
        const bf16x8 av0 = *(const bf16x8*)(Ap0 + k0);
        const bf16x8 av1 = *(const bf16x8*)(Ap1 + k0);
        const bf16x8 bv0 = *(const bf16x8*)(Bp0 + k0);
        const bf16x8 bv1 = *(const bf16x8*)(Bp1 + k0);
        __syncthreads();  // previous iteration's ds_reads done before overwrite
        *(bf16x8*)&aT[r0 * 32 + cc0]        = av0;
        *(bf16x8*)&aT[(r0 + 64) * 32 + cc0] = av1;
        *(bf16x8*)&bT[r0 * 32 + cc0]        = bv0;
        *(bf16x8*)&bT[(r0 + 64) * 32 + cc0] = bv1;
        __syncthreads();
        bf16x8 af[4], bfr[4];
#pragma unroll
        for (int i = 0; i < 4; i++)
            af[i] = *(const bf16x8*)&aT[(wm + i * 16 + lm) * 32 + lk];
#pragma unroll
        for (int i = 0; i < 4; i++)
            bfr[i] = *(const bf16x8*)&bT[(wn + i * 16 + lm) * 32 + lk];
#pragma unroll
        for (int mi = 0; mi < 4; mi++)
#pragma unroll
            for (int ni = 0; ni < 4; ni++)
                acc[mi][ni] = __builtin_amdgcn_mfma_f32_16x16x32_bf16(
                    af[mi], bfr[ni], acc[mi][ni], 0, 0, 0);
    }

    // C/D layout: col = lane&15, row = (lane>>4)*4 + reg
    const int rb = m0 + wm + (lane >> 4) * 4;
    const int cb = n0 + wn + lm;
#pragma unroll
    for (int ni = 0; ni < 4; ni++) {
        const int col = cb + ni * 16;
        const float bv = bias[col];
#pragma unroll
        for (int mi = 0; mi < 4; mi++) {
#pragma unroll
            for (int r2 = 0; r2 < 4; r2++) {
                const int row = rb + mi * 16 + r2;
                float v = acc[mi][ni][r2] + bv;
                if (EPI == 1) {
                    // gelu(v) = v * sigmoid(2*sqrt(2/pi)*(v + 0.044715 v^3))
                    // max |err| vs exact erf-gelu ~1e-3, attenuated through fc2.
                    const float p  = fmaf(v * v, 0.07135481627f, 1.59576912161f);
                    const float u2 = fminf(v * p, 80.f);
                    const float e  = __expf(u2);
                    v = v * e * __builtin_amdgcn_rcpf(1.f + e);
                }
                if (EPI == 2) v += res[(size_t)row * N + col];
                Cc[(size_t)row * N + col] = (TO)v;
            }
        }
    }
}

// ---------------- Windowed attention: one block per (head, window) ----------------
// qkv/out pointers are CHUNK-LOCAL (a whole number of images each).
__global__ __launch_bounds__(256) void attn_k(const bf16* __restrict__ qkv,
    const float* __restrict__ rpb, bf16* __restrict__ out)
{
    const int hd = blockIdx.x;          // 0..11
    const int w  = blockIdx.y;          // 0..64*imgs-1
    const int bb = w >> 6, win = w & 63, wy = win >> 3, wx = win & 7;
    __shared__ int   toks[49];
    __shared__ float biasS[169];
    __shared__ __align__(16) float ks[49][36];
    __shared__ __align__(16) float vs[49][36];
    __shared__ float S[49][50];
    const int tid = threadIdx.x;
    if (tid < 49)
        toks[tid] = bb * 3136 + (wy * 7 + tid / 7) * 56 + wx * 7 + tid % 7;
    if (tid < 169) biasS[tid] = rpb[tid * 12 + hd];
    __syncthreads();
    // stage K,V (fp32) into LDS, 16B global loads
    for (int t = tid; t < 49 * 4; t += 256) {
        const int r = t >> 2, dc = (t & 3) * 8;
        const bf16* p = qkv + (size_t)toks[r] * 1152 + hd * 32 + dc;
        const bf16x8 kv = *(const bf16x8*)(p + 384);
        const bf16x8 vv = *(const bf16x8*)(p + 768);
#pragma unroll
        for (int e = 0; e < 8; e++) { ks[r][dc + e] = (float)kv[e]; vs[r][dc + e] = (float)vv[e]; }
    }
    __syncthreads();
    const int i = tid >> 2, q4 = tid & 3;   // 4 threads cooperate per query row
    if (i < 49) {
        float qr[32];
        const bf16* qp = qkv + (size_t)toks[i] * 1152 + hd * 32;
#pragma unroll
        for (int c = 0; c < 4; c++) {
            const bf16x8 qv = *(const bf16x8*)(qp + c * 8);
#pragma unroll
            for (int e = 0; e < 8; e++) qr[c * 8 + e] = (float)qv[e] * 0.1767766952966369f;
        }
        const int iy = i / 7, ix = i % 7;
        for (int j = q4; j < 49; j += 4) {
            float dot = 0.f;
#pragma unroll
            for (int dc = 0; dc < 8; dc++) {
                const float4 kk = *(const float4*)&ks[j][dc * 4];
                dot += qr[dc*4]*kk.x + qr[dc*4+1]*kk.y + qr[dc*4+2]*kk.z + qr[dc*4+3]*kk.w;
            }
            S[i][j] = dot + biasS[(iy - j / 7 + 6) * 13 + (ix - j % 7 + 6)];
        }
    }
    __syncthreads();
    if (tid < 49) {
        float mx = -1e30f;
        for (int j = 0; j < 49; j++) mx = fmaxf(mx, S[tid][j]);
        float sum = 0.f;
        for (int j = 0; j < 49; j++) { const float e = __expf(S[tid][j] - mx); S[tid][j] = e; sum += e; }
        const float inv = 1.f / sum;
        for (int j = 0; j < 49; j++) S[tid][j] *= inv;
    }
    __syncthreads();
    if (i < 49) {
        const int dc = q4 * 8;
        float acc[8] = {};
        for (int j = 0; j < 49; j++) {
            const float p = S[i][j];
            const float4 v0 = *(const float4*)&vs[j][dc];
            const float4 v1 = *(const float4*)&vs[j][dc + 4];
            acc[0] += p * v0.x; acc[1] += p * v0.y; acc[2] += p * v0.z; acc[3] += p * v0.w;
            acc[4] += p * v1.x; acc[5] += p * v1.y; acc[6] += p * v1.z; acc[7] += p * v1.w;
        }
        bf16x8 pk;
#pragma unroll
        for (int e = 0; e < 8; e++) pk[e] = (bf16)acc[e];
        *(bf16x8*)(out + (size_t)toks[i] * CDIM + hd * 32 + dc) = pk;
    }
}

extern "C" void kernel_launch(void* const* d_in, const int* in_sizes, int n_in,
                              void* d_out, int out_size, void* d_ws, size_t ws_size,
                              hipStream_t stream) {
    // All float tensors are fp32 per the reference; OUTPUT IS FP32 TOO.
    const float* x      = (const float*)d_in[0];
    const float* n1g    = (const float*)d_in[1];
    const float* n1b    = (const float*)d_in[2];
    const float* qkv_w  = (const float*)d_in[3];
    const float* qkv_b  = (const float*)d_in[4];
    const float* rpb    = (const float*)d_in[5];
    const float* proj_w = (const float*)d_in[6];
    const float* proj_b = (const float*)d_in[7];
    const float* n2g    = (const float*)d_in[8];
    const float* n2b    = (const float*)d_in[9];
    const float* fc1_w  = (const float*)d_in[10];
    const float* fc1_b  = (const float*)d_in[11];
    const float* fc2_w  = (const float*)d_in[12];
    const float* fc2_b  = (const float*)d_in[13];
    float* out = (float*)d_out;

    // Workspace layout:
    //   [0, 3538944):            bf16 weights (qkv 442368 | proj 147456 | fc1 589824 | fc2 589824)
    //   [3538944, +rowsC*768):   bufH  (LN out / attn-out chunk, bf16)
    //   [.., +rowsC*3072):       bufB  (qkv chunk 2304 B/row or fc1-out chunk 3072 B/row)
    // x1 (post-attention residual stream, fp32) lives in d_out.
    const size_t wBytes = 3538944;
    int nc = 16;
    for (int c : {1, 2, 4, 8}) {
        if (wBytes + ((size_t)NTOK / c) * 3840 <= ws_size) { nc = c; break; }
    }
    const int rowsC = NTOK / nc;
    const int imgsC = 32 / nc;

    char* ws = (char*)d_ws;
    bf16* wqkv  = (bf16*)ws;
    bf16* wproj = wqkv + 442368;
    bf16* wfc1  = wproj + 147456;
    bf16* wfc2  = wfc1 + 589824;
    bf16* bufH  = (bf16*)(ws + wBytes);
    bf16* bufB  = bufH + (size_t)rowsC * CDIM;
    float* x1   = out;                  // fp32 residual stream in d_out

    // 0) weights fp32 -> bf16
    cvt_k<<<442368 / 1024, 256, 0, stream>>>(qkv_w, wqkv, 442368);
    cvt_k<<<147456 / 1024, 256, 0, stream>>>(proj_w, wproj, 147456);
    cvt_k<<<589824 / 1024, 256, 0, stream>>>(fc1_w, wfc1, 589824);
    cvt_k<<<589824 / 1024, 256, 0, stream>>>(fc2_w, wfc2, 589824);

    // 1) attention path, chunked over images
    for (int c = 0; c < nc; c++) {
        const size_t ro = (size_t)c * rowsC;
        ln32_k<<<rowsC / 4, 256, 0, stream>>>(x + ro * CDIM, n1g, n1b, bufH);
        gemm_bt<0, bf16><<<dim3(1152 / 128, rowsC / 128), 256, 0, stream>>>(
            bufH, wqkv, qkv_b, nullptr, bufB, 1152, 384);
        attn_k<<<dim3(12, 64 * imgsC), 256, 0, stream>>>(bufB, rpb, bufH);
        // x1 = x + attn_out @ proj_w^T + proj_b   (fp32, into d_out)
        gemm_bt<2, float><<<dim3(384 / 128, rowsC / 128), 256, 0, stream>>>(
            bufH, wproj, proj_b, x + ro * CDIM, x1 + ro * CDIM, 384, 384);
    }
    // 2) MLP path, chunked
    for (int c = 0; c < nc; c++) {
        const size_t ro = (size_t)c * rowsC;
        ln32_k<<<rowsC / 4, 256, 0, stream>>>(x1 + ro * CDIM, n2g, n2b, bufH);
        gemm_bt<1, bf16><<<dim3(1536 / 128, rowsC / 128), 256, 0, stream>>>(
            bufH, wfc1, fc1_b, nullptr, bufB, 1536, 384);
        // out = x1 + gelu(h2@fc1^T+b1)@fc2^T + b2  (fp32; res==dst, read-before-write)
        gemm_bt<2, float><<<dim3(384 / 128, rowsC / 128), 256, 0, stream>>>(
            bufB, wfc2, fc2_b, x1 + ro * CDIM, out + ro * CDIM, 384, 1536);
    }
}

// Round 3
// 1231.042 us; speedup vs baseline: 1.1431x; 1.0712x over previous
//
#include <hip/hip_runtime.h>
#include <cstdint>
#include <cstddef>

typedef __bf16 bf16;
typedef __bf16 bf16x4 __attribute__((ext_vector_type(4)));
typedef __bf16 bf16x8 __attribute__((ext_vector_type(8)));
typedef float f32x4 __attribute__((ext_vector_type(4)));

static_assert(sizeof(bf16x8) == 16, "bf16x8 must be 16B");

#define NTOK 100352   // 32 * 3136
#define CDIM 384

#define AS1(p) ((const __attribute__((address_space(1))) void*)(p))
#define AS3(p) ((__attribute__((address_space(3))) void*)(p))

// ---------------- fp32 -> bf16 weight conversion ----------------
__global__ __launch_bounds__(256) void cvt_k(const float* __restrict__ in,
                                             bf16* __restrict__ out, int n)
{
    const int i = (blockIdx.x * 256 + threadIdx.x) * 4;
    if (i < n) {
        const float4 v = *(const float4*)(in + i);
        bf16x4 o;
        o[0] = (bf16)v.x; o[1] = (bf16)v.y; o[2] = (bf16)v.z; o[3] = (bf16)v.w;
        *(bf16x4*)(out + i) = o;
    }
}

// ---------------- LayerNorm, fp32 input -> bf16 output (row per wave) ----------------
__global__ __launch_bounds__(256) void ln32_k(const float* __restrict__ x,
    const float* __restrict__ g, const float* __restrict__ b, bf16* __restrict__ y)
{
    const int wave = threadIdx.x >> 6, lane = threadIdx.x & 63;
    const size_t row = (size_t)blockIdx.x * 4 + wave;
    const float2* xr = (const float2*)(x + row * CDIM);
    float v[6];
    float s = 0.f, s2 = 0.f;
#pragma unroll
    for (int i = 0; i < 3; i++) {
        const float2 t = xr[lane + i * 64];
        v[2 * i] = t.x; v[2 * i + 1] = t.y;
        s += t.x + t.y; s2 += t.x * t.x + t.y * t.y;
    }
#pragma unroll
    for (int off = 32; off > 0; off >>= 1) {
        s  += __shfl_xor(s, off);
        s2 += __shfl_xor(s2, off);
    }
    const float mu   = s * (1.f / CDIM);
    const float rstd = rsqrtf(s2 * (1.f / CDIM) - mu * mu + 1e-5f);
    const float2* gu = (const float2*)g;
    const float2* bu = (const float2*)b;
    uint32_t* yu = (uint32_t*)(y + row * CDIM);
#pragma unroll
    for (int i = 0; i < 3; i++) {
        const float2 gg = gu[lane + i * 64], bb = bu[lane + i * 64];
        const float o0 = (v[2 * i] - mu) * rstd * gg.x + bb.x;
        const float o1 = (v[2 * i + 1] - mu) * rstd * gg.y + bb.y;
        const uint32_t pk = (uint32_t)__builtin_bit_cast(unsigned short, (bf16)o0)
                          | ((uint32_t)__builtin_bit_cast(unsigned short, (bf16)o1) << 16);
        yu[lane + i * 64] = pk;
    }
}

// ---------------- GEMM: C = A(MxK) @ B(NxK)^T + bias [+ gelu | + res] ----------------
// 128x128 tile, BK=32, 4 waves (2x2), each wave 64x64 via 4x4 of 16x16x32 bf16 MFMA.
// Main loop: T3-minimum 2-phase — global_load_lds (width 16) into DOUBLE-buffered
// LDS, ONE barrier per K-step: issue stage(t+1) at loop top, ds_read+MFMA on
// buf[cur] covers the load latency, then a single __syncthreads() (implied
// vmcnt(0)+lgkmcnt(0)) publishes tile t+1. (Round-1 lesson: single-buffered
// gload_lds = stage issued after bar1, drained at bar2 with nothing overlapping
// -> regressed. The dbuf/1-barrier form is the fix.)
// Block swizzle: bijective XCD remap (m204) -> A panels stay in one XCD's L2
// (measured: FETCH_SIZE 308 MB -> 60 MB on fc1).
// EPI: 0 = +bias, 1 = +bias then GELU (tanh form), 2 = +bias +res(fp32)
// bf16 outputs (EPI 0/1) go through an LDS-repack epilogue: 16B/lane coalesced
// stores (raw 32B-granule stores measured 1.85x HBM write amplification).
template <int EPI, typename TO>
__global__ __launch_bounds__(256) void gemm_bt(
    const bf16* __restrict__ A, const bf16* __restrict__ Bm,
    const float* __restrict__ bias, const float* __restrict__ res,
    TO* __restrict__ Cc, int N, int K)
{
    // [buf][a=0/b=1][128 rows x 32 cols]  = 32 KiB total; reused as the
    // 128x128 bf16 C-tile in the EPI 0/1 epilogue (exactly 32 KiB).
    __shared__ __align__(16) bf16 lds[2][2][128 * 32];
    const int tid = threadIdx.x;

    // XCD-bijective swizzle (8 XCDs). orig -> swz, contiguous chunk per XCD.
    const int gx = gridDim.x;
    const int nwg = gx * gridDim.y;
    const int orig = blockIdx.y * gx + blockIdx.x;
    const int q = nwg >> 3, r = nwg & 7;
    const int xcd = orig & 7, lid = orig >> 3;
    const int swz = (xcd < r ? xcd * (q + 1) : r * (q + 1) + (xcd - r) * q) + lid;
    const int m0 = (swz / gx) * 128, n0 = (swz % gx) * 128;

    const int wave = tid >> 6, lane = tid & 63;
    const int wm = (wave >> 1) * 64, wn = (wave & 1) * 64;
    const int lm = lane & 15, lk = (lane >> 4) * 8;

    // staging source coords; LDS dest is wave-uniform base + lane*16 (linear),
    // byte-identical to [row][col] row-major (verified on HW in round 1).
    const int sr = tid >> 2;              // row 0..63 within 64-row panel
    const int sc = (tid & 3) * 8;         // col element 0,8,16,24

    const bf16* Ap0 = A + (size_t)(m0 + sr) * K + sc;
    const bf16* Ap1 = A + (size_t)(m0 + sr + 64) * K + sc;
    const bf16* Bp0 = Bm + (size_t)(n0 + sr) * K + sc;
    const bf16* Bp1 = Bm + (size_t)(n0 + sr + 64) * K + sc;

#define STAGE(buf, koff) do {                                                           \
    __builtin_amdgcn_global_load_lds(AS1(Ap0 + (koff)),                                 \
        AS3(&lds[buf][0][(wave * 16) * 32]), 16, 0, 0);                                 \
    __builtin_amdgcn_global_load_lds(AS1(Ap1 + (koff)),                                 \
        AS3(&lds[buf][0][(64 + wave * 16) * 32]), 16, 0, 0);                            \
    __builtin_amdgcn_global_load_lds(AS1(Bp0 + (koff)),                                 \
        AS3(&lds[buf][1][(wave * 16) * 32]), 16, 0, 0);                                 \
    __builtin_amdgcn_global_load_lds(AS1(Bp1 + (koff)),                                 \
        AS3(&lds[buf][1][(64 + wave * 16) * 32]), 16, 0, 0);                            \
} while (0)

    f32x4 acc[4][4] = {};

    const int nt = K >> 5;
    STAGE(0, 0);
    __syncthreads();
    int cur = 0;
    for (int t = 0; t < nt; ++t) {
        const bool more = (t + 1 < nt);
        if (more) STAGE(cur ^ 1, (t + 1) << 5);
        bf16x8 af[4], bfr[4];
#pragma unroll
        for (int i = 0; i < 4; i++)
            af[i] = *(const bf16x8*)&lds[cur][0][(wm + i * 16 + lm) * 32 + lk];
#pragma unroll
        for (int i = 0; i < 4; i++)
            bfr[i] = *(const bf16x8*)&lds[cur][1][(wn + i * 16 + lm) * 32 + lk];
#pragma unroll
        for (int mi = 0; mi < 4; mi++)
#pragma unroll
            for (int ni = 0; ni < 4; ni++)
                acc[mi][ni] = __builtin_amdgcn_mfma_f32_16x16x32_bf16(
                    af[mi], bfr[ni], acc[mi][ni], 0, 0, 0);
        if (more) { __syncthreads(); cur ^= 1; }
    }
#undef STAGE

    // C/D layout: col = lane&15, row = (lane>>4)*4 + reg
    if (EPI == 2) {
        const int rb = m0 + wm + (lane >> 4) * 4;
        const int cb = n0 + wn + lm;
#pragma unroll
        for (int ni = 0; ni < 4; ni++) {
            const int col = cb + ni * 16;
            const float bv = bias[col];
#pragma unroll
            for (int mi = 0; mi < 4; mi++) {
#pragma unroll
                for (int r2 = 0; r2 < 4; r2++) {
                    const int row = rb + mi * 16 + r2;
                    float v = acc[mi][ni][r2] + bv;
                    v += res[(size_t)row * N + col];
                    Cc[(size_t)row * N + col] = (TO)v;
                }
            }
        }
    } else {
        // bf16 out: repack through LDS for 16B/lane coalesced stores.
        __syncthreads();                       // all ds_reads of last tile done
        bf16* Ct = (bf16*)lds;                 // 128 x 128 bf16 = 32 KiB
        const int rbl = wm + (lane >> 4) * 4;  // block-local row base
        const int cbl = wn + lm;
#pragma unroll
        for (int ni = 0; ni < 4; ni++) {
            const float bv = bias[n0 + cbl + ni * 16];
#pragma unroll
            for (int mi = 0; mi < 4; mi++) {
#pragma unroll
                for (int r2 = 0; r2 < 4; r2++) {
                    float v = acc[mi][ni][r2] + bv;
                    if (EPI == 1) {
                        // gelu(v) = v * sigmoid(2*sqrt(2/pi)*(v + 0.044715 v^3))
                        const float p  = fmaf(v * v, 0.07135481627f, 1.59576912161f);
                        const float u2 = fminf(v * p, 80.f);
                        const float e  = __expf(u2);
                        v = v * e * __builtin_amdgcn_rcpf(1.f + e);
                    }
                    Ct[(rbl + mi * 16 + r2) * 128 + cbl + ni * 16] = (bf16)v;
                }
            }
        }
        __syncthreads();
#pragma unroll
        for (int c2 = 0; c2 < 8; ++c2) {
            const int chunk = tid + (c2 << 8);          // 0..2047
            const int row = chunk >> 4, c8 = (chunk & 15) << 3;
            *(bf16x8*)((bf16*)Cc + (size_t)(m0 + row) * N + n0 + c8) =
                *(const bf16x8*)&Ct[row * 128 + c8];
        }
    }
}

// ---------------- Windowed attention: one block per (head, window) ----------------
// qkv/out pointers are CHUNK-LOCAL (a whole number of images each).
__global__ __launch_bounds__(256) void attn_k(const bf16* __restrict__ qkv,
    const float* __restrict__ rpb, bf16* __restrict__ out)
{
    const int hd = blockIdx.x;          // 0..11
    const int w  = blockIdx.y;          // 0..64*imgs-1
    const int bb = w >> 6, win = w & 63, wy = win >> 3, wx = win & 7;
    __shared__ int   toks[49];
    __shared__ float biasS[169];
    __shared__ __align__(16) float ks[49][36];
    __shared__ __align__(16) float vs[49][36];
    __shared__ float S[49][50];
    const int tid = threadIdx.x;
    if (tid < 49)
        toks[tid] = bb * 3136 + (wy * 7 + tid / 7) * 56 + wx * 7 + tid % 7;
    if (tid < 169) biasS[tid] = rpb[tid * 12 + hd];
    __syncthreads();
    // stage K,V (fp32) into LDS, 16B global loads
    for (int t = tid; t < 49 * 4; t += 256) {
        const int r = t >> 2, dc = (t & 3) * 8;
        const bf16* p = qkv + (size_t)toks[r] * 1152 + hd * 32 + dc;
        const bf16x8 kv = *(const bf16x8*)(p + 384);
        const bf16x8 vv = *(const bf16x8*)(p + 768);
#pragma unroll
        for (int e = 0; e < 8; e++) { ks[r][dc + e] = (float)kv[e]; vs[r][dc + e] = (float)vv[e]; }
    }
    __syncthreads();
    const int i = tid >> 2, q4 = tid & 3;   // 4 threads cooperate per query row
    if (i < 49) {
        float qr[32];
        const bf16* qp = qkv + (size_t)toks[i] * 1152 + hd * 32;
#pragma unroll
        for (int c = 0; c < 4; c++) {
            const bf16x8 qv = *(const bf16x8*)(qp + c * 8);
#pragma unroll
            for (int e = 0; e < 8; e++) qr[c * 8 + e] = (float)qv[e] * 0.1767766952966369f;
        }
        const int iy = i / 7, ix = i % 7;
        for (int j = q4; j < 49; j += 4) {
            float dot = 0.f;
#pragma unroll
            for (int dc = 0; dc < 8; dc++) {
                const float4 kk = *(const float4*)&ks[j][dc * 4];
                dot += qr[dc*4]*kk.x + qr[dc*4+1]*kk.y + qr[dc*4+2]*kk.z + qr[dc*4+3]*kk.w;
            }
            S[i][j] = dot + biasS[(iy - j / 7 + 6) * 13 + (ix - j % 7 + 6)];
        }
    }
    __syncthreads();
    if (tid < 49) {
        float mx = -1e30f;
        for (int j = 0; j < 49; j++) mx = fmaxf(mx, S[tid][j]);
        float sum = 0.f;
        for (int j = 0; j < 49; j++) { const float e = __expf(S[tid][j] - mx); S[tid][j] = e; sum += e; }
        const float inv = 1.f / sum;
        for (int j = 0; j < 49; j++) S[tid][j] *= inv;
    }
    __syncthreads();
    if (i < 49) {
        const int dc = q4 * 8;
        float acc[8] = {};
        for (int j = 0; j < 49; j++) {
            const float p = S[i][j];
            const float4 v0 = *(const float4*)&vs[j][dc];
            const float4 v1 = *(const float4*)&vs[j][dc + 4];
            acc[0] += p * v0.x; acc[1] += p * v0.y; acc[2] += p * v0.z; acc[3] += p * v0.w;
            acc[4] += p * v1.x; acc[5] += p * v1.y; acc[6] += p * v1.z; acc[7] += p * v1.w;
        }
        bf16x8 pk;
#pragma unroll
        for (int e = 0; e < 8; e++) pk[e] = (bf16)acc[e];
        *(bf16x8*)(out + (size_t)toks[i] * CDIM + hd * 32 + dc) = pk;
    }
}

extern "C" void kernel_launch(void* const* d_in, const int* in_sizes, int n_in,
                              void* d_out, int out_size, void* d_ws, size_t ws_size,
                              hipStream_t stream) {
    // All float tensors are fp32 per the reference; OUTPUT IS FP32 TOO.
    const float* x      = (const float*)d_in[0];
    const float* n1g    = (const float*)d_in[1];
    const float* n1b    = (const float*)d_in[2];
    const float* qkv_w  = (const float*)d_in[3];
    const float* qkv_b  = (const float*)d_in[4];
    const float* rpb    = (const float*)d_in[5];
    const float* proj_w = (const float*)d_in[6];
    const float* proj_b = (const float*)d_in[7];
    const float* n2g    = (const float*)d_in[8];
    const float* n2b    = (const float*)d_in[9];
    const float* fc1_w  = (const float*)d_in[10];
    const float* fc1_b  = (const float*)d_in[11];
    const float* fc2_w  = (const float*)d_in[12];
    const float* fc2_b  = (const float*)d_in[13];
    float* out = (float*)d_out;

    // Workspace layout:
    //   [0, 3538944):            bf16 weights (qkv 442368 | proj 147456 | fc1 589824 | fc2 589824)
    //   [3538944, +rowsC*768):   bufH  (LN out / attn-out chunk, bf16)
    //   [.., +rowsC*3072):       bufB  (qkv chunk 2304 B/row or fc1-out chunk 3072 B/row)
    // x1 (post-attention residual stream, fp32) lives in d_out.
    const size_t wBytes = 3538944;
    int nc = 16;
    for (int c : {1, 2, 4, 8}) {
        if (wBytes + ((size_t)NTOK / c) * 3840 <= ws_size) { nc = c; break; }
    }
    const int rowsC = NTOK / nc;
    const int imgsC = 32 / nc;

    char* ws = (char*)d_ws;
    bf16* wqkv  = (bf16*)ws;
    bf16* wproj = wqkv + 442368;
    bf16* wfc1  = wproj + 147456;
    bf16* wfc2  = wfc1 + 589824;
    bf16* bufH  = (bf16*)(ws + wBytes);
    bf16* bufB  = bufH + (size_t)rowsC * CDIM;
    float* x1   = out;                  // fp32 residual stream in d_out

    // 0) weights fp32 -> bf16
    cvt_k<<<442368 / 1024, 256, 0, stream>>>(qkv_w, wqkv, 442368);
    cvt_k<<<147456 / 1024, 256, 0, stream>>>(proj_w, wproj, 147456);
    cvt_k<<<589824 / 1024, 256, 0, stream>>>(fc1_w, wfc1, 589824);
    cvt_k<<<589824 / 1024, 256, 0, stream>>>(fc2_w, wfc2, 589824);

    // 1) attention path, chunked over images
    for (int c = 0; c < nc; c++) {
        const size_t ro = (size_t)c * rowsC;
        ln32_k<<<rowsC / 4, 256, 0, stream>>>(x + ro * CDIM, n1g, n1b, bufH);
        gemm_bt<0, bf16><<<dim3(1152 / 128, rowsC / 128), 256, 0, stream>>>(
            bufH, wqkv, qkv_b, nullptr, bufB, 1152, 384);
        attn_k<<<dim3(12, 64 * imgsC), 256, 0, stream>>>(bufB, rpb, bufH);
        // x1 = x + attn_out @ proj_w^T + proj_b   (fp32, into d_out)
        gemm_bt<2, float><<<dim3(384 / 128, rowsC / 128), 256, 0, stream>>>(
            bufH, wproj, proj_b, x + ro * CDIM, x1 + ro * CDIM, 384, 384);
    }
    // 2) MLP path, chunked
    for (int c = 0; c < nc; c++) {
        const size_t ro = (size_t)c * rowsC;
        ln32_k<<<rowsC / 4, 256, 0, stream>>>(x1 + ro * CDIM, n2g, n2b, bufH);
        gemm_bt<1, bf16><<<dim3(1536 / 128, rowsC / 128), 256, 0, stream>>>(
            bufH, wfc1, fc1_b, nullptr, bufB, 1536, 384);
        // out = x1 + gelu(h2@fc1^T+b1)@fc2^T + b2  (fp32; res==dst, read-before-write)
        gemm_bt<2, float><<<dim3(384 / 128, rowsC / 128), 256, 0, stream>>>(
            bufB, wfc2, fc2_b, x1 + ro * CDIM, out + ro * CDIM, 384, 1536);
    }
}

// Round 4
// 1116.185 us; speedup vs baseline: 1.2607x; 1.1029x over previous
//
#include <hip/hip_runtime.h>
#include <cstdint>
#include <cstddef>

typedef __bf16 bf16;
typedef __bf16 bf16x4 __attribute__((ext_vector_type(4)));
typedef __bf16 bf16x8 __attribute__((ext_vector_type(8)));
typedef float f32x4 __attribute__((ext_vector_type(4)));

static_assert(sizeof(bf16x8) == 16, "bf16x8 must be 16B");

#define NTOK 100352   // 32 * 3136
#define CDIM 384

#define AS1(p) ((const __attribute__((address_space(1))) void*)(p))
#define AS3(p) ((__attribute__((address_space(3))) void*)(p))

// ---------------- fp32 -> bf16 weight conversion ----------------
__global__ __launch_bounds__(256) void cvt_k(const float* __restrict__ in,
                                             bf16* __restrict__ out, int n)
{
    const int i = (blockIdx.x * 256 + threadIdx.x) * 4;
    if (i < n) {
        const float4 v = *(const float4*)(in + i);
        bf16x4 o;
        o[0] = (bf16)v.x; o[1] = (bf16)v.y; o[2] = (bf16)v.z; o[3] = (bf16)v.w;
        *(bf16x4*)(out + i) = o;
    }
}

// ---------------- expanded attention bias table ----------------
// biasE[hd][j(query)][i(key)] (64x64 padded); padded entries = -3e38 so that
// scale*S + bias gives exp()->0 for invalid key tokens (mask via softmax).
__global__ __launch_bounds__(256) void bias_k(const float* __restrict__ rpb,
                                              float* __restrict__ biasE)
{
    const int t = blockIdx.x * 256 + threadIdx.x;   // 12*64*64 = 49152
    const int i = t & 63, j = (t >> 6) & 63, hd = t >> 12;
    float v = -3e38f;
    if (i < 49 && j < 49) {
        const int iy = i / 7, ix = i % 7, jy = j / 7, jx = j % 7;
        v = rpb[((jy - iy + 6) * 13 + (jx - ix + 6)) * 12 + hd];
    }
    biasE[t] = v;
}

// ---------------- LayerNorm, fp32 input -> bf16 output (row per wave) ----------------
__global__ __launch_bounds__(256) void ln32_k(const float* __restrict__ x,
    const float* __restrict__ g, const float* __restrict__ b, bf16* __restrict__ y)
{
    const int wave = threadIdx.x >> 6, lane = threadIdx.x & 63;
    const size_t row = (size_t)blockIdx.x * 4 + wave;
    const float2* xr = (const float2*)(x + row * CDIM);
    float v[6];
    float s = 0.f, s2 = 0.f;
#pragma unroll
    for (int i = 0; i < 3; i++) {
        const float2 t = xr[lane + i * 64];
        v[2 * i] = t.x; v[2 * i + 1] = t.y;
        s += t.x + t.y; s2 += t.x * t.x + t.y * t.y;
    }
#pragma unroll
    for (int off = 32; off > 0; off >>= 1) {
        s  += __shfl_xor(s, off);
        s2 += __shfl_xor(s2, off);
    }
    const float mu   = s * (1.f / CDIM);
    const float rstd = rsqrtf(s2 * (1.f / CDIM) - mu * mu + 1e-5f);
    const float2* gu = (const float2*)g;
    const float2* bu = (const float2*)b;
    uint32_t* yu = (uint32_t*)(y + row * CDIM);
#pragma unroll
    for (int i = 0; i < 3; i++) {
        const float2 gg = gu[lane + i * 64], bb = bu[lane + i * 64];
        const float o0 = (v[2 * i] - mu) * rstd * gg.x + bb.x;
        const float o1 = (v[2 * i + 1] - mu) * rstd * gg.y + bb.y;
        const uint32_t pk = (uint32_t)__builtin_bit_cast(unsigned short, (bf16)o0)
                          | ((uint32_t)__builtin_bit_cast(unsigned short, (bf16)o1) << 16);
        yu[lane + i * 64] = pk;
    }
}

// ---------------- GEMM: C = A(MxK) @ B(NxK)^T + bias [+ gelu | + res] ----------------
// (unchanged from round 3 — dbuf global_load_lds, 1 barrier/K-step, XCD swizzle,
//  LDS-repack epilogue for bf16 outputs)
template <int EPI, typename TO>
__global__ __launch_bounds__(256) void gemm_bt(
    const bf16* __restrict__ A, const bf16* __restrict__ Bm,
    const float* __restrict__ bias, const float* __restrict__ res,
    TO* __restrict__ Cc, int N, int K)
{
    __shared__ __align__(16) bf16 lds[2][2][128 * 32];
    const int tid = threadIdx.x;

    const int gx = gridDim.x;
    const int nwg = gx * gridDim.y;
    const int orig = blockIdx.y * gx + blockIdx.x;
    const int q = nwg >> 3, r = nwg & 7;
    const int xcd = orig & 7, lid = orig >> 3;
    const int swz = (xcd < r ? xcd * (q + 1) : r * (q + 1) + (xcd - r) * q) + lid;
    const int m0 = (swz / gx) * 128, n0 = (swz % gx) * 128;

    const int wave = tid >> 6, lane = tid & 63;
    const int wm = (wave >> 1) * 64, wn = (wave & 1) * 64;
    const int lm = lane & 15, lk = (lane >> 4) * 8;

    const int sr = tid >> 2;
    const int sc = (tid & 3) * 8;

    const bf16* Ap0 = A + (size_t)(m0 + sr) * K + sc;
    const bf16* Ap1 = A + (size_t)(m0 + sr + 64) * K + sc;
    const bf16* Bp0 = Bm + (size_t)(n0 + sr) * K + sc;
    const bf16* Bp1 = Bm + (size_t)(n0 + sr + 64) * K + sc;

#define STAGE(buf, koff) do {                                                           \
    __builtin_amdgcn_global_load_lds(AS1(Ap0 + (koff)),                                 \
        AS3(&lds[buf][0][(wave * 16) * 32]), 16, 0, 0);                                 \
    __builtin_amdgcn_global_load_lds(AS1(Ap1 + (koff)),                                 \
        AS3(&lds[buf][0][(64 + wave * 16) * 32]), 16, 0, 0);                            \
    __builtin_amdgcn_global_load_lds(AS1(Bp0 + (koff)),                                 \
        AS3(&lds[buf][1][(wave * 16) * 32]), 16, 0, 0);                                 \
    __builtin_amdgcn_global_load_lds(AS1(Bp1 + (koff)),                                 \
        AS3(&lds[buf][1][(64 + wave * 16) * 32]), 16, 0, 0);                            \
} while (0)

    f32x4 acc[4][4] = {};

    const int nt = K >> 5;
    STAGE(0, 0);
    __syncthreads();
    int cur = 0;
    for (int t = 0; t < nt; ++t) {
        const bool more = (t + 1 < nt);
        if (more) STAGE(cur ^ 1, (t + 1) << 5);
        bf16x8 af[4], bfr[4];
#pragma unroll
        for (int i = 0; i < 4; i++)
            af[i] = *(const bf16x8*)&lds[cur][0][(wm + i * 16 + lm) * 32 + lk];
#pragma unroll
        for (int i = 0; i < 4; i++)
            bfr[i] = *(const bf16x8*)&lds[cur][1][(wn + i * 16 + lm) * 32 + lk];
#pragma unroll
        for (int mi = 0; mi < 4; mi++)
#pragma unroll
            for (int ni = 0; ni < 4; ni++)
                acc[mi][ni] = __builtin_amdgcn_mfma_f32_16x16x32_bf16(
                    af[mi], bfr[ni], acc[mi][ni], 0, 0, 0);
        if (more) { __syncthreads(); cur ^= 1; }
    }
#undef STAGE

    if (EPI == 2) {
        const int rb = m0 + wm + (lane >> 4) * 4;
        const int cb = n0 + wn + lm;
#pragma unroll
        for (int ni = 0; ni < 4; ni++) {
            const int col = cb + ni * 16;
            const float bv = bias[col];
#pragma unroll
            for (int mi = 0; mi < 4; mi++) {
#pragma unroll
                for (int r2 = 0; r2 < 4; r2++) {
                    const int row = rb + mi * 16 + r2;
                    float v = acc[mi][ni][r2] + bv;
                    v += res[(size_t)row * N + col];
                    Cc[(size_t)row * N + col] = (TO)v;
                }
            }
        }
    } else {
        __syncthreads();
        bf16* Ct = (bf16*)lds;
        const int rbl = wm + (lane >> 4) * 4;
        const int cbl = wn + lm;
#pragma unroll
        for (int ni = 0; ni < 4; ni++) {
            const float bv = bias[n0 + cbl + ni * 16];
#pragma unroll
            for (int mi = 0; mi < 4; mi++) {
#pragma unroll
                for (int r2 = 0; r2 < 4; r2++) {
                    float v = acc[mi][ni][r2] + bv;
                    if (EPI == 1) {
                        const float p  = fmaf(v * v, 0.07135481627f, 1.59576912161f);
                        const float u2 = fminf(v * p, 80.f);
                        const float e  = __expf(u2);
                        v = v * e * __builtin_amdgcn_rcpf(1.f + e);
                    }
                    Ct[(rbl + mi * 16 + r2) * 128 + cbl + ni * 16] = (bf16)v;
                }
            }
        }
        __syncthreads();
#pragma unroll
        for (int c2 = 0; c2 < 8; ++c2) {
            const int chunk = tid + (c2 << 8);
            const int row = chunk >> 4, c8 = (chunk & 15) << 3;
            *(bf16x8*)((bf16*)Cc + (size_t)(m0 + row) * N + n0 + c8) =
                *(const bf16x8*)&Ct[row * 128 + c8];
        }
    }
}

// ---------------- Windowed attention, MFMA version ----------------
// One block per window (all 12 heads); 4 waves x 3 heads sequential.
// Per (wave, head):  S^T = mfma(K, Q)  [swapped operands -> softmax along the
// C-layout ROW dim = wave-parallel via shfl_xor(16,32)];  bias/scale/mask via
// one fma from the precomputed biasE table (-3e38 in padded slots -> exp = 0);
// P -> LDS bf16 XOR-swizzled;  out^T = mfma(V^T, P).  V^T staged per head,
// XOR-swizzled, zero-padded.  All LDS is wave-private -> no barriers in the
// head loop (same-wave DS ops execute in order).
__global__ __launch_bounds__(256) void attn_k(const bf16* __restrict__ qkv,
    const float* __restrict__ biasE, bf16* __restrict__ out)
{
    const int w  = blockIdx.x;          // window id (chunk-local)
    const int bb = w >> 6, win = w & 63, wy = win >> 3, wx = win & 7;
    __shared__ int toks[64];
    __shared__ __align__(16) bf16 VT[4][32 * 64];   // per-wave V^T [d][i], swizzled
    __shared__ __align__(16) bf16 P[4][64 * 64];    // per-wave P   [j][i], swizzled
    const int tid = threadIdx.x;
    if (tid < 64) {
        const int t = tid < 49 ? tid : 48;          // clamp pad tokens
        toks[tid] = bb * 3136 + (wy * 7 + t / 7) * 56 + wx * 7 + t % 7;
    }
    __syncthreads();

    const int wave = tid >> 6, lane = tid & 63;
    const int g = lane >> 4, lr = lane & 15;
    char* vt = (char*)VT[wave];
    char* pb = (char*)P[wave];

    for (int hh = 0; hh < 3; ++hh) {
        const int hd = wave * 3 + hh;
        // ---- stage V^T (swizzled byte ^= (d&7)<<4), zero-fill rows i>=49 ----
#pragma unroll
        for (int c = 0; c < 4; ++c) {
            const int idx = c * 64 + lane;          // 0..255
            const int row = idx >> 2, d0 = (idx & 3) * 8;
            if (row < 49) {
                const bf16x8 vv = *(const bf16x8*)(qkv + (size_t)toks[row] * 1152 + 768 + hd * 32 + d0);
#pragma unroll
                for (int e = 0; e < 8; ++e) {
                    const int d = d0 + e;
                    *(bf16*)(vt + (((d * 64 + row) * 2) ^ ((d & 7) << 4))) = vv[e];
                }
            } else {
#pragma unroll
                for (int e = 0; e < 8; ++e) {
                    const int d = d0 + e;
                    *(bf16*)(vt + (((d * 64 + row) * 2) ^ ((d & 7) << 4))) = (bf16)0.f;
                }
            }
        }
        // ---- Q/K fragments straight from global (frag row = lane&15) ----
        bf16x8 kf[4], qf[4];
#pragma unroll
        for (int b = 0; b < 4; ++b) {
            const size_t rk = (size_t)toks[b * 16 + lr] * 1152;
            kf[b] = *(const bf16x8*)(qkv + rk + 384 + hd * 32 + g * 8);
            qf[b] = *(const bf16x8*)(qkv + rk +       hd * 32 + g * 8);
        }
        // ---- S^T = K @ Q^T : row=i (key), col=j (query) ----
        f32x4 s[4][4] = {};
#pragma unroll
        for (int mi = 0; mi < 4; ++mi)
#pragma unroll
            for (int nj = 0; nj < 4; ++nj)
                s[mi][nj] = __builtin_amdgcn_mfma_f32_16x16x32_bf16(kf[mi], qf[nj], s[mi][nj], 0, 0, 0);
        // ---- softmax along i per column j; write P[j][i] bf16 swizzled ----
        const float* bh = biasE + hd * 4096;
#pragma unroll
        for (int nj = 0; nj < 4; ++nj) {
            const int j = nj * 16 + lr;
            const float* bj = bh + j * 64 + g * 4;
            float mx = -3e38f;
#pragma unroll
            for (int mi = 0; mi < 4; ++mi) {
                const float4 be = *(const float4*)(bj + mi * 16);
                const float* bp4 = (const float*)&be;
#pragma unroll
                for (int r2 = 0; r2 < 4; ++r2) {
                    const float v = fmaf(s[mi][nj][r2], 0.1767766952966369f, bp4[r2]);
                    s[mi][nj][r2] = v;
                    mx = fmaxf(mx, v);
                }
            }
            mx = fmaxf(mx, __shfl_xor(mx, 16));
            mx = fmaxf(mx, __shfl_xor(mx, 32));
            float sm = 0.f;
#pragma unroll
            for (int mi = 0; mi < 4; ++mi)
#pragma unroll
                for (int r2 = 0; r2 < 4; ++r2) {
                    const float e = __expf(s[mi][nj][r2] - mx);
                    s[mi][nj][r2] = e;
                    sm += e;
                }
            sm += __shfl_xor(sm, 16);
            sm += __shfl_xor(sm, 32);
            const float inv = __builtin_amdgcn_rcpf(sm);
#pragma unroll
            for (int mi = 0; mi < 4; ++mi) {
                bf16x4 pk;
#pragma unroll
                for (int r2 = 0; r2 < 4; ++r2) pk[r2] = (bf16)(s[mi][nj][r2] * inv);
                const int i0 = mi * 16 + g * 4;
                *(bf16x4*)(pb + (((j * 64 + i0) * 2) ^ ((j & 7) << 4))) = pk;
            }
        }
        // ---- out^T(d,j) = mfma(A=V^T, B=P), contraction over i (2x32) ----
        f32x4 o[2][4] = {};
#pragma unroll
        for (int kb = 0; kb < 2; ++kb) {
            bf16x8 av[2], bp[4];
#pragma unroll
            for (int db = 0; db < 2; ++db) {
                const int d = db * 16 + lr;
                av[db] = *(const bf16x8*)(vt + (((d * 64 + kb * 32 + g * 8) * 2) ^ ((d & 7) << 4)));
            }
#pragma unroll
            for (int jb = 0; jb < 4; ++jb) {
                const int j = jb * 16 + lr;
                bp[jb] = *(const bf16x8*)(pb + (((j * 64 + kb * 32 + g * 8) * 2) ^ ((j & 7) << 4)));
            }
#pragma unroll
            for (int db = 0; db < 2; ++db)
#pragma unroll
                for (int jb = 0; jb < 4; ++jb)
                    o[db][jb] = __builtin_amdgcn_mfma_f32_16x16x32_bf16(av[db], bp[jb], o[db][jb], 0, 0, 0);
        }
        // ---- store: C layout row = d = db*16+g*4+r, col = j ----
#pragma unroll
        for (int jb = 0; jb < 4; ++jb) {
            const int j = jb * 16 + lr;
            if (j < 49) {
                bf16* op = out + (size_t)toks[j] * CDIM + hd * 32 + g * 4;
#pragma unroll
                for (int db = 0; db < 2; ++db) {
                    bf16x4 pk;
#pragma unroll
                    for (int r2 = 0; r2 < 4; ++r2) pk[r2] = (bf16)o[db][jb][r2];
                    *(bf16x4*)(op + db * 16) = pk;
                }
            }
        }
    }
}

extern "C" void kernel_launch(void* const* d_in, const int* in_sizes, int n_in,
                              void* d_out, int out_size, void* d_ws, size_t ws_size,
                              hipStream_t stream) {
    const float* x      = (const float*)d_in[0];
    const float* n1g    = (const float*)d_in[1];
    const float* n1b    = (const float*)d_in[2];
    const float* qkv_w  = (const float*)d_in[3];
    const float* qkv_b  = (const float*)d_in[4];
    const float* rpb    = (const float*)d_in[5];
    const float* proj_w = (const float*)d_in[6];
    const float* proj_b = (const float*)d_in[7];
    const float* n2g    = (const float*)d_in[8];
    const float* n2b    = (const float*)d_in[9];
    const float* fc1_w  = (const float*)d_in[10];
    const float* fc1_b  = (const float*)d_in[11];
    const float* fc2_w  = (const float*)d_in[12];
    const float* fc2_b  = (const float*)d_in[13];
    float* out = (float*)d_out;

    // Workspace layout:
    //   [0, 3538944):            bf16 weights (qkv | proj | fc1 | fc2)
    //   [3538944, 3735552):      biasE fp32 [12][64][64]
    //   [3735552, +rowsC*768):   bufH  (LN out / attn-out chunk, bf16)
    //   [.., +rowsC*3072):       bufB  (qkv chunk or fc1-out chunk)
    const size_t wBytes = 3538944 + 196608;
    int nc = 16;
    for (int c : {1, 2, 4, 8}) {
        if (wBytes + ((size_t)NTOK / c) * 3840 <= ws_size) { nc = c; break; }
    }
    const int rowsC = NTOK / nc;
    const int imgsC = 32 / nc;

    char* ws = (char*)d_ws;
    bf16* wqkv  = (bf16*)ws;
    bf16* wproj = wqkv + 442368;
    bf16* wfc1  = wproj + 147456;
    bf16* wfc2  = wfc1 + 589824;
    float* biasE = (float*)(ws + 3538944);
    bf16* bufH  = (bf16*)(ws + wBytes);
    bf16* bufB  = bufH + (size_t)rowsC * CDIM;
    float* x1   = out;

    // 0) weights fp32 -> bf16, bias table
    cvt_k<<<442368 / 1024, 256, 0, stream>>>(qkv_w, wqkv, 442368);
    cvt_k<<<147456 / 1024, 256, 0, stream>>>(proj_w, wproj, 147456);
    cvt_k<<<589824 / 1024, 256, 0, stream>>>(fc1_w, wfc1, 589824);
    cvt_k<<<589824 / 1024, 256, 0, stream>>>(fc2_w, wfc2, 589824);
    bias_k<<<192, 256, 0, stream>>>(rpb, biasE);

    // 1) attention path, chunked over images
    for (int c = 0; c < nc; c++) {
        const size_t ro = (size_t)c * rowsC;
        ln32_k<<<rowsC / 4, 256, 0, stream>>>(x + ro * CDIM, n1g, n1b, bufH);
        gemm_bt<0, bf16><<<dim3(1152 / 128, rowsC / 128), 256, 0, stream>>>(
            bufH, wqkv, qkv_b, nullptr, bufB, 1152, 384);
        attn_k<<<dim3(64 * imgsC), 256, 0, stream>>>(bufB, biasE, bufH);
        gemm_bt<2, float><<<dim3(384 / 128, rowsC / 128), 256, 0, stream>>>(
            bufH, wproj, proj_b, x + ro * CDIM, x1 + ro * CDIM, 384, 384);
    }
    // 2) MLP path, chunked
    for (int c = 0; c < nc; c++) {
        const size_t ro = (size_t)c * rowsC;
        ln32_k<<<rowsC / 4, 256, 0, stream>>>(x1 + ro * CDIM, n2g, n2b, bufH);
        gemm_bt<1, bf16><<<dim3(1536 / 128, rowsC / 128), 256, 0, stream>>>(
            bufH, wfc1, fc1_b, nullptr, bufB, 1536, 384);
        gemm_bt<2, float><<<dim3(384 / 128, rowsC / 128), 256, 0, stream>>>(
            bufB, wfc2, fc2_b, x1 + ro * CDIM, out + ro * CDIM, 384, 1536);
    }
}

// Round 6
// 1079.108 us; speedup vs baseline: 1.3041x; 1.0344x over previous
//
#include <hip/hip_runtime.h>
#include <cstdint>
#include <cstddef>

typedef __bf16 bf16;
typedef __bf16 bf16x4 __attribute__((ext_vector_type(4)));
typedef __bf16 bf16x8 __attribute__((ext_vector_type(8)));
typedef float f32x4 __attribute__((ext_vector_type(4)));

static_assert(sizeof(bf16x8) == 16, "bf16x8 must be 16B");

#define NTOK 100352   // 32 * 3136
#define CDIM 384

#define AS1(p) ((const __attribute__((address_space(1))) void*)(p))
#define AS3(p) ((__attribute__((address_space(3))) void*)(p))

// ---------------- fp32 -> bf16 weight conversion ----------------
__global__ __launch_bounds__(256) void cvt_k(const float* __restrict__ in,
                                             bf16* __restrict__ out, int n)
{
    const int i = (blockIdx.x * 256 + threadIdx.x) * 4;
    if (i < n) {
        const float4 v = *(const float4*)(in + i);
        bf16x4 o;
        o[0] = (bf16)v.x; o[1] = (bf16)v.y; o[2] = (bf16)v.z; o[3] = (bf16)v.w;
        *(bf16x4*)(out + i) = o;
    }
}

// ---------------- expanded attention bias table ----------------
// biasE[hd][j(query)][i(key)] (64x64 padded); padded entries = -3e38 so that
// scale*S + bias gives exp()->0 for invalid key tokens (mask via softmax).
__global__ __launch_bounds__(256) void bias_k(const float* __restrict__ rpb,
                                              float* __restrict__ biasE)
{
    const int t = blockIdx.x * 256 + threadIdx.x;   // 12*64*64 = 49152
    const int i = t & 63, j = (t >> 6) & 63, hd = t >> 12;
    float v = -3e38f;
    if (i < 49 && j < 49) {
        const int iy = i / 7, ix = i % 7, jy = j / 7, jx = j % 7;
        v = rpb[((jy - iy + 6) * 13 + (jx - ix + 6)) * 12 + hd];
    }
    biasE[t] = v;
}

// ---------------- LayerNorm, fp32 input -> bf16 output (row per wave) ----------------
__global__ __launch_bounds__(256) void ln32_k(const float* __restrict__ x,
    const float* __restrict__ g, const float* __restrict__ b, bf16* __restrict__ y)
{
    const int wave = threadIdx.x >> 6, lane = threadIdx.x & 63;
    const size_t row = (size_t)blockIdx.x * 4 + wave;
    const float2* xr = (const float2*)(x + row * CDIM);
    float v[6];
    float s = 0.f, s2 = 0.f;
#pragma unroll
    for (int i = 0; i < 3; i++) {
        const float2 t = xr[lane + i * 64];
        v[2 * i] = t.x; v[2 * i + 1] = t.y;
        s += t.x + t.y; s2 += t.x * t.x + t.y * t.y;
    }
#pragma unroll
    for (int off = 32; off > 0; off >>= 1) {
        s  += __shfl_xor(s, off);
        s2 += __shfl_xor(s2, off);
    }
    const float mu   = s * (1.f / CDIM);
    const float rstd = rsqrtf(s2 * (1.f / CDIM) - mu * mu + 1e-5f);
    const float2* gu = (const float2*)g;
    const float2* bu = (const float2*)b;
    uint32_t* yu = (uint32_t*)(y + row * CDIM);
#pragma unroll
    for (int i = 0; i < 3; i++) {
        const float2 gg = gu[lane + i * 64], bb = bu[lane + i * 64];
        const float o0 = (v[2 * i] - mu) * rstd * gg.x + bb.x;
        const float o1 = (v[2 * i + 1] - mu) * rstd * gg.y + bb.y;
        const uint32_t pk = (uint32_t)__builtin_bit_cast(unsigned short, (bf16)o0)
                          | ((uint32_t)__builtin_bit_cast(unsigned short, (bf16)o1) << 16);
        yu[lane + i * 64] = pk;
    }
}

// ---------------- GEMM: C = A(MxK) @ B(NxK)^T + bias [+ gelu | + res] ----------------
// 128x128 tile, BK=32, 4 waves (2x2), each wave 64x64 via 4x4 of 16x16x32 bf16 MFMA.
// Pipeline (T3+T4): DEPTH-3 LDS buffers, counted vmcnt — STAGE(t+2) issued at
// iter t, waited (vmcnt(8): 2 newer stages stay in flight) at barrier #1 of
// the iteration that reads it => every staged load gets ~2 iterations
// (>1000 cy) of cover; vmcnt never drains to 0 in the main loop.
//   Hazards: STAGE at iter t writes buf[(t+2)%3]==buf[(t-1)%3]; its readers all
//   crossed barrier #2 of iter t-1 (ds_reads consumed by MFMA before that
//   barrier). buf[t%3] validity = counted vmcnt + barrier #1.
// LDS granule swizzle (T2, both-sides per rule 21): ds_read_b128 rows stride
// 64 B -> banks depend only on row&1 -> 8-way conflict (measured 1.4e7).
// 16B-granule swizzle g' = g ^ ((row>>1)&3): PRE-SWIZZLE the per-thread GLOBAL
// source column (LDS dest stays linear for global_load_lds) and XOR the read
// offset. Verified: lanes 0-7 cover all 32 banks once; 2 lanes/bank = free.
// Block swizzle: bijective XCD remap -> A panels stay in one XCD's L2.
// EPI: 0 = +bias, 1 = +bias then GELU (tanh form), 2 = +bias +res(fp32)
template <int EPI, typename TO>
__global__ __launch_bounds__(256) void gemm_bt(
    const bf16* __restrict__ A, const bf16* __restrict__ Bm,
    const float* __restrict__ bias, const float* __restrict__ res,
    TO* __restrict__ Cc, int N, int K)
{
    __shared__ __align__(16) bf16 lds[3][2][128 * 32];   // 48 KiB
    const int tid = threadIdx.x;

    const int gx = gridDim.x;
    const int nwg = gx * gridDim.y;
    const int orig = blockIdx.y * gx + blockIdx.x;
    const int q = nwg >> 3, r = nwg & 7;
    const int xcd = orig & 7, lid = orig >> 3;
    const int swz = (xcd < r ? xcd * (q + 1) : r * (q + 1) + (xcd - r) * q) + lid;
    const int m0 = (swz / gx) * 128, n0 = (swz % gx) * 128;

    const int wave = tid >> 6, lane = tid & 63;
    const int wm = (wave >> 1) * 64, wn = (wave & 1) * 64;
    const int lm = lane & 15;
    // read-side swizzled granule offset (i-independent: wm+16i is 16-aligned)
    const int lko = (((lane >> 4) ^ ((lm >> 1) & 3)) & 3) * 8;

    // staging: thread tid owns LDS (row sr | sr+64, granule tid&3); source
    // column pre-swizzled so LDS slot (row,g) holds global granule g^((row>>1)&3)
    const int sr = tid >> 2;
    const int sc = (((tid & 3) ^ ((sr >> 1) & 3)) & 3) * 8;

    const bf16* Ap0 = A + (size_t)(m0 + sr) * K + sc;
    const bf16* Ap1 = A + (size_t)(m0 + sr + 64) * K + sc;
    const bf16* Bp0 = Bm + (size_t)(n0 + sr) * K + sc;
    const bf16* Bp1 = Bm + (size_t)(n0 + sr + 64) * K + sc;

#define STAGE(buf, koff) do {                                                           \
    __builtin_amdgcn_global_load_lds(AS1(Ap0 + (koff)),                                 \
        AS3(&lds[buf][0][(wave * 16) * 32]), 16, 0, 0);                                 \
    __builtin_amdgcn_global_load_lds(AS1(Ap1 + (koff)),                                 \
        AS3(&lds[buf][0][(64 + wave * 16) * 32]), 16, 0, 0);                            \
    __builtin_amdgcn_global_load_lds(AS1(Bp0 + (koff)),                                 \
        AS3(&lds[buf][1][(wave * 16) * 32]), 16, 0, 0);                                 \
    __builtin_amdgcn_global_load_lds(AS1(Bp1 + (koff)),                                 \
        AS3(&lds[buf][1][(64 + wave * 16) * 32]), 16, 0, 0);                            \
} while (0)

    f32x4 acc[4][4] = {};

    const int nt = K >> 5;          // >= 12 for all call sites
    STAGE(0, 0);
    STAGE(1, 32);
    int bi = 0;                     // t % 3
    for (int t = 0; t < nt; ++t) {
        if (t + 2 < nt) {
            const int b2 = bi ? bi - 1 : 2;             // (t+2) % 3
            STAGE(b2, (t + 2) << 5);
            asm volatile("s_waitcnt vmcnt(8)" ::: "memory");
        } else if (t + 1 < nt) {
            asm volatile("s_waitcnt vmcnt(4)" ::: "memory");
        } else {
            asm volatile("s_waitcnt vmcnt(0)" ::: "memory");
        }
        __builtin_amdgcn_sched_barrier(0);              // pin: nothing crosses the wait
        __builtin_amdgcn_s_barrier();                   // buf[bi] fully staged
        bf16x8 af[4], bfr[4];
#pragma unroll
        for (int i = 0; i < 4; i++)
            af[i] = *(const bf16x8*)&lds[bi][0][(wm + i * 16 + lm) * 32 + lko];
#pragma unroll
        for (int i = 0; i < 4; i++)
            bfr[i] = *(const bf16x8*)&lds[bi][1][(wn + i * 16 + lm) * 32 + lko];
#pragma unroll
        for (int mi = 0; mi < 4; mi++)
#pragma unroll
            for (int ni = 0; ni < 4; ni++)
                acc[mi][ni] = __builtin_amdgcn_mfma_f32_16x16x32_bf16(
                    af[mi], bfr[ni], acc[mi][ni], 0, 0, 0);
        if (t + 1 < nt) {
            __builtin_amdgcn_sched_barrier(0);          // reads of buf[bi] stay above
            __builtin_amdgcn_s_barrier();               // reads of buf[bi] done
        }
        bi = (bi == 2) ? 0 : bi + 1;
    }
#undef STAGE

    if (EPI == 2) {
        const int rb = m0 + wm + (lane >> 4) * 4;
        const int cb = n0 + wn + lm;
#pragma unroll
        for (int ni = 0; ni < 4; ni++) {
            const int col = cb + ni * 16;
            const float bv = bias[col];
#pragma unroll
            for (int mi = 0; mi < 4; mi++) {
#pragma unroll
                for (int r2 = 0; r2 < 4; r2++) {
                    const int row = rb + mi * 16 + r2;
                    float v = acc[mi][ni][r2] + bv;
                    v += res[(size_t)row * N + col];
                    Cc[(size_t)row * N + col] = (TO)v;
                }
            }
        }
    } else {
        // bf16 out: repack through LDS (first 32 KiB) for coalesced stores.
        __syncthreads();
        bf16* Ct = (bf16*)lds;
        const int rbl = wm + (lane >> 4) * 4;
        const int cbl = wn + lm;
#pragma unroll
        for (int ni = 0; ni < 4; ni++) {
            const float bv = bias[n0 + cbl + ni * 16];
#pragma unroll
            for (int mi = 0; mi < 4; mi++) {
#pragma unroll
                for (int r2 = 0; r2 < 4; r2++) {
                    float v = acc[mi][ni][r2] + bv;
                    if (EPI == 1) {
                        const float p  = fmaf(v * v, 0.07135481627f, 1.59576912161f);
                        const float u2 = fminf(v * p, 80.f);
                        const float e  = __expf(u2);
                        v = v * e * __builtin_amdgcn_rcpf(1.f + e);
                    }
                    Ct[(rbl + mi * 16 + r2) * 128 + cbl + ni * 16] = (bf16)v;
                }
            }
        }
        __syncthreads();
#pragma unroll
        for (int c2 = 0; c2 < 8; ++c2) {
            const int chunk = tid + (c2 << 8);
            const int row = chunk >> 4, c8 = (chunk & 15) << 3;
            *(bf16x8*)((bf16*)Cc + (size_t)(m0 + row) * N + n0 + c8) =
                *(const bf16x8*)&Ct[row * 128 + c8];
        }
    }
}

// ---------------- Windowed attention, MFMA version (unchanged) ----------------
__global__ __launch_bounds__(256) void attn_k(const bf16* __restrict__ qkv,
    const float* __restrict__ biasE, bf16* __restrict__ out)
{
    const int w  = blockIdx.x;          // window id (chunk-local)
    const int bb = w >> 6, win = w & 63, wy = win >> 3, wx = win & 7;
    __shared__ int toks[64];
    __shared__ __align__(16) bf16 VT[4][32 * 64];   // per-wave V^T [d][i], swizzled
    __shared__ __align__(16) bf16 P[4][64 * 64];    // per-wave P   [j][i], swizzled
    const int tid = threadIdx.x;
    if (tid < 64) {
        const int t = tid < 49 ? tid : 48;          // clamp pad tokens
        toks[tid] = bb * 3136 + (wy * 7 + t / 7) * 56 + wx * 7 + t % 7;
    }
    __syncthreads();

    const int wave = tid >> 6, lane = tid & 63;
    const int g = lane >> 4, lr = lane & 15;
    char* vt = (char*)VT[wave];
    char* pb = (char*)P[wave];

    for (int hh = 0; hh < 3; ++hh) {
        const int hd = wave * 3 + hh;
#pragma unroll
        for (int c = 0; c < 4; ++c) {
            const int idx = c * 64 + lane;          // 0..255
            const int row = idx >> 2, d0 = (idx & 3) * 8;
            if (row < 49) {
                const bf16x8 vv = *(const bf16x8*)(qkv + (size_t)toks[row] * 1152 + 768 + hd * 32 + d0);
#pragma unroll
                for (int e = 0; e < 8; ++e) {
                    const int d = d0 + e;
                    *(bf16*)(vt + (((d * 64 + row) * 2) ^ ((d & 7) << 4))) = vv[e];
                }
            } else {
#pragma unroll
                for (int e = 0; e < 8; ++e) {
                    const int d = d0 + e;
                    *(bf16*)(vt + (((d * 64 + row) * 2) ^ ((d & 7) << 4))) = (bf16)0.f;
                }
            }
        }
        bf16x8 kf[4], qf[4];
#pragma unroll
        for (int b = 0; b < 4; ++b) {
            const size_t rk = (size_t)toks[b * 16 + lr] * 1152;
            kf[b] = *(const bf16x8*)(qkv + rk + 384 + hd * 32 + g * 8);
            qf[b] = *(const bf16x8*)(qkv + rk +       hd * 32 + g * 8);
        }
        f32x4 s[4][4] = {};
#pragma unroll
        for (int mi = 0; mi < 4; ++mi)
#pragma unroll
            for (int nj = 0; nj < 4; ++nj)
                s[mi][nj] = __builtin_amdgcn_mfma_f32_16x16x32_bf16(kf[mi], qf[nj], s[mi][nj], 0, 0, 0);
        const float* bh = biasE + hd * 4096;
#pragma unroll
        for (int nj = 0; nj < 4; ++nj) {
            const int j = nj * 16 + lr;
            const float* bj = bh + j * 64 + g * 4;
            float mx = -3e38f;
#pragma unroll
            for (int mi = 0; mi < 4; ++mi) {
                const float4 be = *(const float4*)(bj + mi * 16);
                const float* bp4 = (const float*)&be;
#pragma unroll
                for (int r2 = 0; r2 < 4; ++r2) {
                    const float v = fmaf(s[mi][nj][r2], 0.1767766952966369f, bp4[r2]);
                    s[mi][nj][r2] = v;
                    mx = fmaxf(mx, v);
                }
            }
            mx = fmaxf(mx, __shfl_xor(mx, 16));
            mx = fmaxf(mx, __shfl_xor(mx, 32));
            float sm = 0.f;
#pragma unroll
            for (int mi = 0; mi < 4; ++mi)
#pragma unroll
                for (int r2 = 0; r2 < 4; ++r2) {
                    const float e = __expf(s[mi][nj][r2] - mx);
                    s[mi][nj][r2] = e;
                    sm += e;
                }
            sm += __shfl_xor(sm, 16);
            sm += __shfl_xor(sm, 32);
            const float inv = __builtin_amdgcn_rcpf(sm);
#pragma unroll
            for (int mi = 0; mi < 4; ++mi) {
                bf16x4 pk;
#pragma unroll
                for (int r2 = 0; r2 < 4; ++r2) pk[r2] = (bf16)(s[mi][nj][r2] * inv);
                const int i0 = mi * 16 + g * 4;
                *(bf16x4*)(pb + (((j * 64 + i0) * 2) ^ ((j & 7) << 4))) = pk;
            }
        }
        f32x4 o[2][4] = {};
#pragma unroll
        for (int kb = 0; kb < 2; ++kb) {
            bf16x8 av[2], bp[4];
#pragma unroll
            for (int db = 0; db < 2; ++db) {
                const int d = db * 16 + lr;
                av[db] = *(const bf16x8*)(vt + (((d * 64 + kb * 32 + g * 8) * 2) ^ ((d & 7) << 4)));
            }
#pragma unroll
            for (int jb = 0; jb < 4; ++jb) {
                const int j = jb * 16 + lr;
                bp[jb] = *(const bf16x8*)(pb + (((j * 64 + kb * 32 + g * 8) * 2) ^ ((j & 7) << 4)));
            }
#pragma unroll
            for (int db = 0; db < 2; ++db)
#pragma unroll
                for (int jb = 0; jb < 4; ++jb)
                    o[db][jb] = __builtin_amdgcn_mfma_f32_16x16x32_bf16(av[db], bp[jb], o[db][jb], 0, 0, 0);
        }
#pragma unroll
        for (int jb = 0; jb < 4; ++jb) {
            const int j = jb * 16 + lr;
            if (j < 49) {
                bf16* op = out + (size_t)toks[j] * CDIM + hd * 32 + g * 4;
#pragma unroll
                for (int db = 0; db < 2; ++db) {
                    bf16x4 pk;
#pragma unroll
                    for (int r2 = 0; r2 < 4; ++r2) pk[r2] = (bf16)o[db][jb][r2];
                    *(bf16x4*)(op + db * 16) = pk;
                }
            }
        }
    }
}

extern "C" void kernel_launch(void* const* d_in, const int* in_sizes, int n_in,
                              void* d_out, int out_size, void* d_ws, size_t ws_size,
                              hipStream_t stream) {
    const float* x      = (const float*)d_in[0];
    const float* n1g    = (const float*)d_in[1];
    const float* n1b    = (const float*)d_in[2];
    const float* qkv_w  = (const float*)d_in[3];
    const float* qkv_b  = (const float*)d_in[4];
    const float* rpb    = (const float*)d_in[5];
    const float* proj_w = (const float*)d_in[6];
    const float* proj_b = (const float*)d_in[7];
    const float* n2g    = (const float*)d_in[8];
    const float* n2b    = (const float*)d_in[9];
    const float* fc1_w  = (const float*)d_in[10];
    const float* fc1_b  = (const float*)d_in[11];
    const float* fc2_w  = (const float*)d_in[12];
    const float* fc2_b  = (const float*)d_in[13];
    float* out = (float*)d_out;

    const size_t wBytes = 3538944 + 196608;
    int nc = 16;
    for (int c : {1, 2, 4, 8}) {
        if (wBytes + ((size_t)NTOK / c) * 3840 <= ws_size) { nc = c; break; }
    }
    const int rowsC = NTOK / nc;
    const int imgsC = 32 / nc;

    char* ws = (char*)d_ws;
    bf16* wqkv  = (bf16*)ws;
    bf16* wproj = wqkv + 442368;
    bf16* wfc1  = wproj + 147456;
    bf16* wfc2  = wfc1 + 589824;
    float* biasE = (float*)(ws + 3538944);
    bf16* bufH  = (bf16*)(ws + wBytes);
    bf16* bufB  = bufH + (size_t)rowsC * CDIM;
    float* x1   = out;

    cvt_k<<<442368 / 1024, 256, 0, stream>>>(qkv_w, wqkv, 442368);
    cvt_k<<<147456 / 1024, 256, 0, stream>>>(proj_w, wproj, 147456);
    cvt_k<<<589824 / 1024, 256, 0, stream>>>(fc1_w, wfc1, 589824);
    cvt_k<<<589824 / 1024, 256, 0, stream>>>(fc2_w, wfc2, 589824);
    bias_k<<<192, 256, 0, stream>>>(rpb, biasE);

    for (int c = 0; c < nc; c++) {
        const size_t ro = (size_t)c * rowsC;
        ln32_k<<<rowsC / 4, 256, 0, stream>>>(x + ro * CDIM, n1g, n1b, bufH);
        gemm_bt<0, bf16><<<dim3(1152 / 128, rowsC / 128), 256, 0, stream>>>(
            bufH, wqkv, qkv_b, nullptr, bufB, 1152, 384);
        attn_k<<<dim3(64 * imgsC), 256, 0, stream>>>(bufB, biasE, bufH);
        gemm_bt<2, float><<<dim3(384 / 128, rowsC / 128), 256, 0, stream>>>(
            bufH, wproj, proj_b, x + ro * CDIM, x1 + ro * CDIM, 384, 384);
    }
    for (int c = 0; c < nc; c++) {
        const size_t ro = (size_t)c * rowsC;
        ln32_k<<<rowsC / 4, 256, 0, stream>>>(x1 + ro * CDIM, n2g, n2b, bufH);
        gemm_bt<1, bf16><<<dim3(1536 / 128, rowsC / 128), 256, 0, stream>>>(
            bufH, wfc1, fc1_b, nullptr, bufB, 1536, 384);
        gemm_bt<2, float><<<dim3(384 / 128, rowsC / 128), 256, 0, stream>>>(
            bufB, wfc2, fc2_b, x1 + ro * CDIM, out + ro * CDIM, 384, 1536);
    }
}

// Round 7
// 1072.386 us; speedup vs baseline: 1.3122x; 1.0063x over previous
//
#include <hip/hip_runtime.h>
#include <cstdint>
#include <cstddef>

typedef __bf16 bf16;
typedef __bf16 bf16x4 __attribute__((ext_vector_type(4)));
typedef __bf16 bf16x8 __attribute__((ext_vector_type(8)));
typedef float f32x4 __attribute__((ext_vector_type(4)));

static_assert(sizeof(bf16x8) == 16, "bf16x8 must be 16B");

#define NTOK 100352   // 32 * 3136
#define CDIM 384

#define AS1(p) ((const __attribute__((address_space(1))) void*)(p))
#define AS3(p) ((__attribute__((address_space(3))) void*)(p))

// ---------------- fp32 -> bf16 weight conversion ----------------
__global__ __launch_bounds__(256) void cvt_k(const float* __restrict__ in,
                                             bf16* __restrict__ out, int n)
{
    const int i = (blockIdx.x * 256 + threadIdx.x) * 4;
    if (i < n) {
        const float4 v = *(const float4*)(in + i);
        bf16x4 o;
        o[0] = (bf16)v.x; o[1] = (bf16)v.y; o[2] = (bf16)v.z; o[3] = (bf16)v.w;
        *(bf16x4*)(out + i) = o;
    }
}

// ---------------- expanded attention bias table ----------------
__global__ __launch_bounds__(256) void bias_k(const float* __restrict__ rpb,
                                              float* __restrict__ biasE)
{
    const int t = blockIdx.x * 256 + threadIdx.x;   // 12*64*64 = 49152
    const int i = t & 63, j = (t >> 6) & 63, hd = t >> 12;
    float v = -3e38f;
    if (i < 49 && j < 49) {
        const int iy = i / 7, ix = i % 7, jy = j / 7, jx = j % 7;
        v = rpb[((jy - iy + 6) * 13 + (jx - ix + 6)) * 12 + hd];
    }
    biasE[t] = v;
}

// ---------------- LayerNorm, fp32 input -> bf16 output (row per wave) ----------------
__global__ __launch_bounds__(256) void ln32_k(const float* __restrict__ x,
    const float* __restrict__ g, const float* __restrict__ b, bf16* __restrict__ y)
{
    const int wave = threadIdx.x >> 6, lane = threadIdx.x & 63;
    const size_t row = (size_t)blockIdx.x * 4 + wave;
    const float2* xr = (const float2*)(x + row * CDIM);
    float v[6];
    float s = 0.f, s2 = 0.f;
#pragma unroll
    for (int i = 0; i < 3; i++) {
        const float2 t = xr[lane + i * 64];
        v[2 * i] = t.x; v[2 * i + 1] = t.y;
        s += t.x + t.y; s2 += t.x * t.x + t.y * t.y;
    }
#pragma unroll
    for (int off = 32; off > 0; off >>= 1) {
        s  += __shfl_xor(s, off);
        s2 += __shfl_xor(s2, off);
    }
    const float mu   = s * (1.f / CDIM);
    const float rstd = rsqrtf(s2 * (1.f / CDIM) - mu * mu + 1e-5f);
    const float2* gu = (const float2*)g;
    const float2* bu = (const float2*)b;
    uint32_t* yu = (uint32_t*)(y + row * CDIM);
#pragma unroll
    for (int i = 0; i < 3; i++) {
        const float2 gg = gu[lane + i * 64], bb = bu[lane + i * 64];
        const float o0 = (v[2 * i] - mu) * rstd * gg.x + bb.x;
        const float o1 = (v[2 * i + 1] - mu) * rstd * gg.y + bb.y;
        const uint32_t pk = (uint32_t)__builtin_bit_cast(unsigned short, (bf16)o0)
                          | ((uint32_t)__builtin_bit_cast(unsigned short, (bf16)o1) << 16);
        yu[lane + i * 64] = pk;
    }
}

// ---------------- GEMM: C = A(MxK) @ B(NxK)^T + bias [+ gelu | + res] ----------------
// 256x128 tile, BK=32, 4 waves; each wave owns 64 rows x FULL 128 cols:
// 4 A-frags + 8 B-frags -> 32 MFMA (16x16x32) per iter. Rationale (round-6
// post-mortem): nothing was saturated (LDS 36%, MFMA 22%, HBM 24%) -> the cost
// was per-iteration sync overhead. This tile doubles FLOP per barrier and cuts
// LDS traffic/FLOP 25%.
// Pipeline: depth-3 buffers, prefetch distance 1, ONE barrier per iter.
//   Safety: STAGE(t+1)->buf[(t+1)%3]; its last readers ran at iter t-2 and
//   their ds_reads completed before barrier(t-1) (MFMAs consumed them), and
//   every wave issuing STAGE(t+1) has passed barrier(t) -> no overwrite hazard.
//   vmcnt(6) completes the oldest stage only; never drains to 0 in-loop (T4).
// LDS granule swizzle (T2, both-sides): proven round 6 (conflicts 1.4e7 -> 0).
// Block swizzle: bijective XCD remap -> A panels stay in one XCD's L2.
// EPI: 0 = +bias, 1 = +bias then GELU (tanh form), 2 = +bias +res(fp32)
template <int EPI, typename TO>
__global__ __launch_bounds__(256, 2) void gemm_bt(
    const bf16* __restrict__ A, const bf16* __restrict__ Bm,
    const float* __restrict__ bias, const float* __restrict__ res,
    TO* __restrict__ Cc, int N, int K)
{
    // per buffer: A 256x32 | B 128x32 (bf16) = 24 KiB; x3 = 72 KiB.
    // Epilogue reuses as 256x128 bf16 C-tile (64 KiB).
    __shared__ __align__(16) bf16 lds[3][384 * 32];
    const int tid = threadIdx.x;

    const int gx = gridDim.x;
    const int nwg = gx * gridDim.y;
    const int orig = blockIdx.y * gx + blockIdx.x;
    const int q = nwg >> 3, r = nwg & 7;
    const int xcd = orig & 7, lid = orig >> 3;
    const int swz = (xcd < r ? xcd * (q + 1) : r * (q + 1) + (xcd - r) * q) + lid;
    const int m0 = (swz / gx) * 256, n0 = (swz % gx) * 128;

    const int wave = tid >> 6, lane = tid & 63;
    const int wm = wave * 64;               // wave's 64 output rows
    const int lm = lane & 15;
    // read-side swizzled granule (row>>1 bits cancel: wm, 16i, 256-offset are 16-aligned)
    const int lko = (((lane >> 4) ^ ((lm >> 1) & 3)) & 3) * 8;

    // staging: thread tid covers row tid>>2 of each 64-row panel, granule tid&3;
    // source column pre-swizzled so LDS slot (row,g) holds global granule g^((row>>1)&3)
    const int sr = tid >> 2;
    const int sc = (((tid & 3) ^ ((sr >> 1) & 3)) & 3) * 8;

    const bf16* Ap0 = A + (size_t)(m0 + sr) * K + sc;
    const bf16* Ap1 = A + (size_t)(m0 + 64 + sr) * K + sc;
    const bf16* Ap2 = A + (size_t)(m0 + 128 + sr) * K + sc;
    const bf16* Ap3 = A + (size_t)(m0 + 192 + sr) * K + sc;
    const bf16* Bp0 = Bm + (size_t)(n0 + sr) * K + sc;
    const bf16* Bp1 = Bm + (size_t)(n0 + 64 + sr) * K + sc;

#define STAGE(buf, koff) do {                                                            \
    __builtin_amdgcn_global_load_lds(AS1(Ap0 + (koff)),                                  \
        AS3(&lds[buf][(  0 + wave * 16) * 32]), 16, 0, 0);                               \
    __builtin_amdgcn_global_load_lds(AS1(Ap1 + (koff)),                                  \
        AS3(&lds[buf][( 64 + wave * 16) * 32]), 16, 0, 0);                               \
    __builtin_amdgcn_global_load_lds(AS1(Ap2 + (koff)),                                  \
        AS3(&lds[buf][(128 + wave * 16) * 32]), 16, 0, 0);                               \
    __builtin_amdgcn_global_load_lds(AS1(Ap3 + (koff)),                                  \
        AS3(&lds[buf][(192 + wave * 16) * 32]), 16, 0, 0);                               \
    __builtin_amdgcn_global_load_lds(AS1(Bp0 + (koff)),                                  \
        AS3(&lds[buf][(256 + wave * 16) * 32]), 16, 0, 0);                               \
    __builtin_amdgcn_global_load_lds(AS1(Bp1 + (koff)),                                  \
        AS3(&lds[buf][(320 + wave * 16) * 32]), 16, 0, 0);                               \
} while (0)

    f32x4 acc[4][8] = {};

    const int nt = K >> 5;          // 12 or 48 for all call sites
    STAGE(0, 0);
    int bi = 0;                     // t % 3
    for (int t = 0; t < nt; ++t) {
        if (t + 1 < nt) {
            const int bn = (bi == 2) ? 0 : bi + 1;
            STAGE(bn, (t + 1) << 5);
            asm volatile("s_waitcnt vmcnt(6)" ::: "memory");  // oldest stage done
        } else {
            asm volatile("s_waitcnt vmcnt(0)" ::: "memory");
        }
        __builtin_amdgcn_s_barrier();                         // buf[bi] published
        __builtin_amdgcn_sched_barrier(0);                    // no read hoists above
        bf16x8 af[4], bfr[8];
#pragma unroll
        for (int i = 0; i < 4; i++)
            af[i] = *(const bf16x8*)&lds[bi][(wm + i * 16 + lm) * 32 + lko];
#pragma unroll
        for (int j = 0; j < 8; j++)
            bfr[j] = *(const bf16x8*)&lds[bi][(256 + j * 16 + lm) * 32 + lko];
#pragma unroll
        for (int mi = 0; mi < 4; mi++)
#pragma unroll
            for (int nj = 0; nj < 8; nj++)
                acc[mi][nj] = __builtin_amdgcn_mfma_f32_16x16x32_bf16(
                    af[mi], bfr[nj], acc[mi][nj], 0, 0, 0);
        bi = (bi == 2) ? 0 : bi + 1;
    }
#undef STAGE

    // C/D layout: col = lane&15, row = (lane>>4)*4 + reg
    if (EPI == 2) {
        const int rb = m0 + wm + (lane >> 4) * 4;
        const int cb = n0 + lm;
#pragma unroll
        for (int nj = 0; nj < 8; nj++) {
            const int col = cb + nj * 16;
            const float bv = bias[col];
#pragma unroll
            for (int mi = 0; mi < 4; mi++) {
#pragma unroll
                for (int r2 = 0; r2 < 4; r2++) {
                    const int row = rb + mi * 16 + r2;
                    float v = acc[mi][nj][r2] + bv;
                    v += res[(size_t)row * N + col];
                    Cc[(size_t)row * N + col] = (TO)v;
                }
            }
        }
    } else {
        // bf16 out: repack through LDS (256x128 = 64 KiB) for coalesced stores.
        __syncthreads();
        bf16* Ct = (bf16*)lds;
        const int rbl = wm + (lane >> 4) * 4;
#pragma unroll
        for (int nj = 0; nj < 8; nj++) {
            const float bv = bias[n0 + lm + nj * 16];
#pragma unroll
            for (int mi = 0; mi < 4; mi++) {
#pragma unroll
                for (int r2 = 0; r2 < 4; r2++) {
                    float v = acc[mi][nj][r2] + bv;
                    if (EPI == 1) {
                        const float p  = fmaf(v * v, 0.07135481627f, 1.59576912161f);
                        const float u2 = fminf(v * p, 80.f);
                        const float e  = __expf(u2);
                        v = v * e * __builtin_amdgcn_rcpf(1.f + e);
                    }
                    Ct[(rbl + mi * 16 + r2) * 128 + lm + nj * 16] = (bf16)v;
                }
            }
        }
        __syncthreads();
#pragma unroll
        for (int c2 = 0; c2 < 16; ++c2) {
            const int chunk = tid + (c2 << 8);          // 0..4095
            const int row = chunk >> 4, c8 = (chunk & 15) << 3;
            *(bf16x8*)((bf16*)Cc + (size_t)(m0 + row) * N + n0 + c8) =
                *(const bf16x8*)&Ct[row * 128 + c8];
        }
    }
}

// ---------------- Windowed attention, MFMA version (unchanged) ----------------
__global__ __launch_bounds__(256) void attn_k(const bf16* __restrict__ qkv,
    const float* __restrict__ biasE, bf16* __restrict__ out)
{
    const int w  = blockIdx.x;          // window id (chunk-local)
    const int bb = w >> 6, win = w & 63, wy = win >> 3, wx = win & 7;
    __shared__ int toks[64];
    __shared__ __align__(16) bf16 VT[4][32 * 64];   // per-wave V^T [d][i], swizzled
    __shared__ __align__(16) bf16 P[4][64 * 64];    // per-wave P   [j][i], swizzled
    const int tid = threadIdx.x;
    if (tid < 64) {
        const int t = tid < 49 ? tid : 48;          // clamp pad tokens
        toks[tid] = bb * 3136 + (wy * 7 + t / 7) * 56 + wx * 7 + t % 7;
    }
    __syncthreads();

    const int wave = tid >> 6, lane = tid & 63;
    const int g = lane >> 4, lr = lane & 15;
    char* vt = (char*)VT[wave];
    char* pb = (char*)P[wave];

    for (int hh = 0; hh < 3; ++hh) {
        const int hd = wave * 3 + hh;
#pragma unroll
        for (int c = 0; c < 4; ++c) {
            const int idx = c * 64 + lane;          // 0..255
            const int row = idx >> 2, d0 = (idx & 3) * 8;
            if (row < 49) {
                const bf16x8 vv = *(const bf16x8*)(qkv + (size_t)toks[row] * 1152 + 768 + hd * 32 + d0);
#pragma unroll
                for (int e = 0; e < 8; ++e) {
                    const int d = d0 + e;
                    *(bf16*)(vt + (((d * 64 + row) * 2) ^ ((d & 7) << 4))) = vv[e];
                }
            } else {
#pragma unroll
                for (int e = 0; e < 8; ++e) {
                    const int d = d0 + e;
                    *(bf16*)(vt + (((d * 64 + row) * 2) ^ ((d & 7) << 4))) = (bf16)0.f;
                }
            }
        }
        bf16x8 kf[4], qf[4];
#pragma unroll
        for (int b = 0; b < 4; ++b) {
            const size_t rk = (size_t)toks[b * 16 + lr] * 1152;
            kf[b] = *(const bf16x8*)(qkv + rk + 384 + hd * 32 + g * 8);
            qf[b] = *(const bf16x8*)(qkv + rk +       hd * 32 + g * 8);
        }
        f32x4 s[4][4] = {};
#pragma unroll
        for (int mi = 0; mi < 4; ++mi)
#pragma unroll
            for (int nj = 0; nj < 4; ++nj)
                s[mi][nj] = __builtin_amdgcn_mfma_f32_16x16x32_bf16(kf[mi], qf[nj], s[mi][nj], 0, 0, 0);
        const float* bh = biasE + hd * 4096;
#pragma unroll
        for (int nj = 0; nj < 4; ++nj) {
            const int j = nj * 16 + lr;
            const float* bj = bh + j * 64 + g * 4;
            float mx = -3e38f;
#pragma unroll
            for (int mi = 0; mi < 4; ++mi) {
                const float4 be = *(const float4*)(bj + mi * 16);
                const float* bp4 = (const float*)&be;
#pragma unroll
                for (int r2 = 0; r2 < 4; ++r2) {
                    const float v = fmaf(s[mi][nj][r2], 0.1767766952966369f, bp4[r2]);
                    s[mi][nj][r2] = v;
                    mx = fmaxf(mx, v);
                }
            }
            mx = fmaxf(mx, __shfl_xor(mx, 16));
            mx = fmaxf(mx, __shfl_xor(mx, 32));
            float sm = 0.f;
#pragma unroll
            for (int mi = 0; mi < 4; ++mi)
#pragma unroll
                for (int r2 = 0; r2 < 4; ++r2) {
                    const float e = __expf(s[mi][nj][r2] - mx);
                    s[mi][nj][r2] = e;
                    sm += e;
                }
            sm += __shfl_xor(sm, 16);
            sm += __shfl_xor(sm, 32);
            const float inv = __builtin_amdgcn_rcpf(sm);
#pragma unroll
            for (int mi = 0; mi < 4; ++mi) {
                bf16x4 pk;
#pragma unroll
                for (int r2 = 0; r2 < 4; ++r2) pk[r2] = (bf16)(s[mi][nj][r2] * inv);
                const int i0 = mi * 16 + g * 4;
                *(bf16x4*)(pb + (((j * 64 + i0) * 2) ^ ((j & 7) << 4))) = pk;
            }
        }
        f32x4 o[2][4] = {};
#pragma unroll
        for (int kb = 0; kb < 2; ++kb) {
            bf16x8 av[2], bp[4];
#pragma unroll
            for (int db = 0; db < 2; ++db) {
                const int d = db * 16 + lr;
                av[db] = *(const bf16x8*)(vt + (((d * 64 + kb * 32 + g * 8) * 2) ^ ((d & 7) << 4)));
            }
#pragma unroll
            for (int jb = 0; jb < 4; ++jb) {
                const int j = jb * 16 + lr;
                bp[jb] = *(const bf16x8*)(pb + (((j * 64 + kb * 32 + g * 8) * 2) ^ ((j & 7) << 4)));
            }
#pragma unroll
            for (int db = 0; db < 2; ++db)
#pragma unroll
                for (int jb = 0; jb < 4; ++jb)
                    o[db][jb] = __builtin_amdgcn_mfma_f32_16x16x32_bf16(av[db], bp[jb], o[db][jb], 0, 0, 0);
        }
#pragma unroll
        for (int jb = 0; jb < 4; ++jb) {
            const int j = jb * 16 + lr;
            if (j < 49) {
                bf16* op = out + (size_t)toks[j] * CDIM + hd * 32 + g * 4;
#pragma unroll
                for (int db = 0; db < 2; ++db) {
                    bf16x4 pk;
#pragma unroll
                    for (int r2 = 0; r2 < 4; ++r2) pk[r2] = (bf16)o[db][jb][r2];
                    *(bf16x4*)(op + db * 16) = pk;
                }
            }
        }
    }
}

extern "C" void kernel_launch(void* const* d_in, const int* in_sizes, int n_in,
                              void* d_out, int out_size, void* d_ws, size_t ws_size,
                              hipStream_t stream) {
    const float* x      = (const float*)d_in[0];
    const float* n1g    = (const float*)d_in[1];
    const float* n1b    = (const float*)d_in[2];
    const float* qkv_w  = (const float*)d_in[3];
    const float* qkv_b  = (const float*)d_in[4];
    const float* rpb    = (const float*)d_in[5];
    const float* proj_w = (const float*)d_in[6];
    const float* proj_b = (const float*)d_in[7];
    const float* n2g    = (const float*)d_in[8];
    const float* n2b    = (const float*)d_in[9];
    const float* fc1_w  = (const float*)d_in[10];
    const float* fc1_b  = (const float*)d_in[11];
    const float* fc2_w  = (const float*)d_in[12];
    const float* fc2_b  = (const float*)d_in[13];
    float* out = (float*)d_out;

    const size_t wBytes = 3538944 + 196608;
    int nc = 8;                         // rowsC must stay a multiple of 256
    for (int c : {1, 2, 4, 8}) {
        if (wBytes + ((size_t)NTOK / c) * 3840 <= ws_size) { nc = c; break; }
    }
    const int rowsC = NTOK / nc;
    const int imgsC = 32 / nc;

    char* ws = (char*)d_ws;
    bf16* wqkv  = (bf16*)ws;
    bf16* wproj = wqkv + 442368;
    bf16* wfc1  = wproj + 147456;
    bf16* wfc2  = wfc1 + 589824;
    float* biasE = (float*)(ws + 3538944);
    bf16* bufH  = (bf16*)(ws + wBytes);
    bf16* bufB  = bufH + (size_t)rowsC * CDIM;
    float* x1   = out;

    cvt_k<<<442368 / 1024, 256, 0, stream>>>(qkv_w, wqkv, 442368);
    cvt_k<<<147456 / 1024, 256, 0, stream>>>(proj_w, wproj, 147456);
    cvt_k<<<589824 / 1024, 256, 0, stream>>>(fc1_w, wfc1, 589824);
    cvt_k<<<589824 / 1024, 256, 0, stream>>>(fc2_w, wfc2, 589824);
    bias_k<<<192, 256, 0, stream>>>(rpb, biasE);

    for (int c = 0; c < nc; c++) {
        const size_t ro = (size_t)c * rowsC;
        ln32_k<<<rowsC / 4, 256, 0, stream>>>(x + ro * CDIM, n1g, n1b, bufH);
        gemm_bt<0, bf16><<<dim3(1152 / 128, rowsC / 256), 256, 0, stream>>>(
            bufH, wqkv, qkv_b, nullptr, bufB, 1152, 384);
        attn_k<<<dim3(64 * imgsC), 256, 0, stream>>>(bufB, biasE, bufH);
        gemm_bt<2, float><<<dim3(384 / 128, rowsC / 256), 256, 0, stream>>>(
            bufH, wproj, proj_b, x + ro * CDIM, x1 + ro * CDIM, 384, 384);
    }
    for (int c = 0; c < nc; c++) {
        const size_t ro = (size_t)c * rowsC;
        ln32_k<<<rowsC / 4, 256, 0, stream>>>(x1 + ro * CDIM, n2g, n2b, bufH);
        gemm_bt<1, bf16><<<dim3(1536 / 128, rowsC / 256), 256, 0, stream>>>(
            bufH, wfc1, fc1_b, nullptr, bufB, 1536, 384);
        gemm_bt<2, float><<<dim3(384 / 128, rowsC / 256), 256, 0, stream>>>(
            bufB, wfc2, fc2_b, x1 + ro * CDIM, out + ro * CDIM, 384, 1536);
    }
}